// Round 7
// baseline (404.797 us; speedup 1.0000x reference)
//
#include <hip/hip_runtime.h>

static constexpr int NUM_GRAPHS = 64;
static constexpr int DH = 64;      // hidden dim == wave size
static constexpr int DOUT = 7;
static constexpr int BSH = 16;     // nodes per dst-bucket (shift 4)

// ---------- CSR build: dst-bucketed two-level counting sort ----------
// A: count edges per bucket
__global__ void bcount_kernel(const int* __restrict__ ei, int* __restrict__ bcnt, int E) {
    int e = blockIdx.x * blockDim.x + threadIdx.x;
    if (e < E) atomicAdd(&bcnt[ei[E + e] >> 4], 1);
}

// B: single-block exclusive scan over B bucket counts (B <= 4096)
__global__ __launch_bounds__(1024) void bscan_kernel(const int* __restrict__ bcnt,
                                                     int* __restrict__ bptr,
                                                     int* __restrict__ bcur, int B) {
    __shared__ int sh[1024];
    int t = threadIdx.x;
    int per = (B + 1023) / 1024;
    int s = t * per, e = min(B, s + per);
    int sum = 0;
    for (int i = s; i < e; ++i) sum += bcnt[i];
    sh[t] = sum;
    __syncthreads();
    for (int off = 1; off < 1024; off <<= 1) {
        int v = (t >= off) ? sh[t - off] : 0;
        __syncthreads();
        sh[t] += v;
        __syncthreads();
    }
    int run = (t == 0) ? 0 : sh[t - 1];
    for (int i = s; i < e; ++i) {
        int c = bcnt[i];
        bptr[i] = run;
        bcur[i] = run;
        run += c;
    }
    if (t == 1023) bptr[B] = run;   // == E
}

// C: scatter edges into bucket-grouped ebuf (writes ~sequential per bucket)
__global__ void bscatter_kernel(const int* __restrict__ ei, int* __restrict__ bcur,
                                int2* __restrict__ ebuf, int E) {
    int e = blockIdx.x * blockDim.x + threadIdx.x;
    if (e >= E) return;
    int src = ei[e], dst = ei[E + e];
    int p = atomicAdd(&bcur[dst >> 4], 1);
    ebuf[p] = make_int2(src, dst);
}

// D: per-bucket node degrees -> rowptr (global positions), dinv
__global__ __launch_bounds__(256) void bnode_kernel(const int2* __restrict__ ebuf,
                                                    const int* __restrict__ bptr,
                                                    int* __restrict__ rowptr,
                                                    float* __restrict__ dinv, int N, int E) {
    __shared__ int cnt[BSH];
    __shared__ int pos0[BSH];
    int b = blockIdx.x, t = threadIdx.x;
    if (t < BSH) cnt[t] = 0;
    __syncthreads();
    int beg = bptr[b], end = bptr[b + 1];
    for (int i = beg + t; i < end; i += 256)
        atomicAdd(&cnt[ebuf[i].y & (BSH - 1)], 1);
    __syncthreads();
    if (t == 0) {
        int run = beg;
        for (int j = 0; j < BSH; ++j) { pos0[j] = run; run += cnt[j]; }
    }
    __syncthreads();
    int v0 = b * BSH;
    if (t < BSH && v0 + t < N) {
        rowptr[v0 + t] = pos0[t];
        dinv[v0 + t] = rsqrtf((float)(cnt[t] + 1));   // +1: self-loop
    }
    if (b == 0 && t == 0) rowptr[N] = E;
}

// E: per-bucket CSR fill (writes land in the bucket's contiguous csr range)
__global__ __launch_bounds__(256) void bfill_kernel(const int2* __restrict__ ebuf,
                                                    const int* __restrict__ bptr,
                                                    const int* __restrict__ rowptr,
                                                    const float* __restrict__ dinv,
                                                    int2* __restrict__ csr, int N) {
    __shared__ int cur[BSH];
    __shared__ float sdinv[BSH];
    int b = blockIdx.x, t = threadIdx.x;
    int v0 = b * BSH;
    if (t < BSH) {
        int v = v0 + t;
        cur[t] = (v < N) ? rowptr[v] : 0;
        sdinv[t] = (v < N) ? dinv[v] : 0.f;
    }
    __syncthreads();
    int beg = bptr[b], end = bptr[b + 1];
    for (int i = beg + t; i < end; i += 256) {
        int2 ed = ebuf[i];
        int l = ed.y & (BSH - 1);
        int p = atomicAdd(&cur[l], 1);
        float w = dinv[ed.x] * sdinv[l];
        csr[p] = make_int2(ed.x, __float_as_int(w));
    }
}

// ---------- dense GEMM: h[N,64] = x[N,K] @ W[K,64] ----------
// Block = 256 threads = 4 waves, 64 rows/block. W tile + x tile staged in LDS.
template <int K>
__global__ __launch_bounds__(256) void gemm_kernel(const float* __restrict__ x,
                                                   const float* __restrict__ W,
                                                   float* __restrict__ h, int N) {
    __shared__ float4 sX4[64][K / 4];
    __shared__ float  sW[K][64];
    int t = threadIdx.x;
    int r0 = blockIdx.x * 64;

    const float4* W4 = (const float4*)W;
    for (int v = t; v < K * 16; v += 256) {
        int k = v >> 4, c4 = v & 15;
        *(float4*)&sW[k][c4 * 4] = W4[v];
    }
    for (int v = t; v < 64 * (K / 4); v += 256) {
        int row = v / (K / 4), c4 = v % (K / 4);
        int gr = min(r0 + row, N - 1);
        sX4[row][c4] = *(const float4*)(x + (size_t)gr * K + 4 * c4);
    }
    __syncthreads();

    int c = t & 63;
    int w = t >> 6;
    float acc[16];
#pragma unroll
    for (int r = 0; r < 16; ++r) acc[r] = 0.f;

#pragma unroll 2
    for (int k4 = 0; k4 < K / 4; ++k4) {
        float w0 = sW[4 * k4 + 0][c];
        float w1 = sW[4 * k4 + 1][c];
        float w2 = sW[4 * k4 + 2][c];
        float w3 = sW[4 * k4 + 3][c];
#pragma unroll
        for (int r = 0; r < 16; ++r) {
            float4 xv = sX4[w * 16 + r][k4];    // broadcast
            acc[r] = fmaf(xv.x, w0, acc[r]);
            acc[r] = fmaf(xv.y, w1, acc[r]);
            acc[r] = fmaf(xv.z, w2, acc[r]);
            acc[r] = fmaf(xv.w, w3, acc[r]);
        }
    }

#pragma unroll
    for (int r = 0; r < 16; ++r) {
        int row = r0 + w * 16 + r;
        if (row < N) h[(size_t)row * DH + c] = acc[r];
    }
}

// ---------- sparse aggregation: one wave per node, lane = channel ----------
__global__ __launch_bounds__(256) void agg_kernel(const float* __restrict__ h,
                                                  const int2* __restrict__ csr,
                                                  const int* __restrict__ rowptr,
                                                  const float* __restrict__ dinv,
                                                  const float* __restrict__ bias,
                                                  float* __restrict__ out, int N) {
    int lane = threadIdx.x & 63;
    int node = blockIdx.x * (blockDim.x >> 6) + (threadIdx.x >> 6);
    if (node >= N) return;
    float di = dinv[node];
    float a0 = di * di * h[(size_t)node * DH + lane];   // self-loop term
    float a1 = 0.f, a2 = 0.f, a3 = 0.f, a4 = 0.f, a5 = 0.f, a6 = 0.f, a7 = 0.f;
    int beg = rowptr[node], end = rowptr[node + 1];
    int i = beg;
    for (; i + 8 <= end; i += 8) {
        int2 e0 = csr[i + 0]; int2 e1 = csr[i + 1];
        int2 e2 = csr[i + 2]; int2 e3 = csr[i + 3];
        int2 e4 = csr[i + 4]; int2 e5 = csr[i + 5];
        int2 e6 = csr[i + 6]; int2 e7 = csr[i + 7];
        a0 = fmaf(__int_as_float(e0.y), h[(size_t)e0.x * DH + lane], a0);
        a1 = fmaf(__int_as_float(e1.y), h[(size_t)e1.x * DH + lane], a1);
        a2 = fmaf(__int_as_float(e2.y), h[(size_t)e2.x * DH + lane], a2);
        a3 = fmaf(__int_as_float(e3.y), h[(size_t)e3.x * DH + lane], a3);
        a4 = fmaf(__int_as_float(e4.y), h[(size_t)e4.x * DH + lane], a4);
        a5 = fmaf(__int_as_float(e5.y), h[(size_t)e5.x * DH + lane], a5);
        a6 = fmaf(__int_as_float(e6.y), h[(size_t)e6.x * DH + lane], a6);
        a7 = fmaf(__int_as_float(e7.y), h[(size_t)e7.x * DH + lane], a7);
    }
    for (; i < end; ++i) {
        int2 e = csr[i];
        a0 = fmaf(__int_as_float(e.y), h[(size_t)e.x * DH + lane], a0);
    }
    float acc = ((a0 + a1) + (a2 + a3)) + ((a4 + a5) + (a6 + a7));
    out[(size_t)node * DH + lane] = fmaxf(acc + bias[lane], 0.f);
}

// ---------- mean pool over sorted batch (JK-cat of x1,x2) ----------
__global__ __launch_bounds__(128) void pool_kernel(const float* __restrict__ x1,
                                                   const float* __restrict__ x2,
                                                   const int* __restrict__ batch,
                                                   float* __restrict__ pool,
                                                   float* __restrict__ cntf,
                                                   int N, int nodesPerBlock) {
    int f = threadIdx.x;  // 0..127
    int start = blockIdx.x * nodesPerBlock;
    int end = min(N, start + nodesPerBlock);
    if (start >= end) return;
    int gcur = batch[start];
    float acc = 0.f;
    int c = 0;
    for (int v = start; v < end; ++v) {
        int g = batch[v];               // uniform across block
        if (g != gcur) {
            atomicAdd(&pool[gcur * 128 + f], acc);
            if (f == 0) atomicAdd(&cntf[gcur], (float)c);
            acc = 0.f; c = 0; gcur = g;
        }
        acc += (f < DH) ? x1[(size_t)v * DH + f] : x2[(size_t)v * DH + (f - DH)];
        ++c;
    }
    atomicAdd(&pool[gcur * 128 + f], acc);
    if (f == 0) atomicAdd(&cntf[gcur], (float)c);
}

// ---------- head: (pool/cnt) @ Wlin + blin ----------
__global__ __launch_bounds__(512) void final_kernel(const float* __restrict__ pool,
                                                    const float* __restrict__ cntf,
                                                    const float* __restrict__ Wlin,
                                                    const float* __restrict__ blin,
                                                    float* __restrict__ out) {
    int t = threadIdx.x;
    if (t >= NUM_GRAPHS * DOUT) return;
    int g = t / DOUT, o = t % DOUT;
    float inv = 1.0f / fmaxf(cntf[g], 1.0f);
    float acc = 0.f;
    for (int k = 0; k < 2 * DH; ++k)
        acc = fmaf(pool[g * 128 + k], Wlin[k * DOUT + o], acc);
    out[t] = acc * inv + blin[o];
}

extern "C" void kernel_launch(void* const* d_in, const int* in_sizes, int n_in,
                              void* d_out, int out_size, void* d_ws, size_t ws_size,
                              hipStream_t stream) {
    const float* x    = (const float*)d_in[0];
    const int*   ei   = (const int*)d_in[1];
    const int*   batch= (const int*)d_in[2];
    const float* W1   = (const float*)d_in[3];
    const float* b1   = (const float*)d_in[4];
    const float* W2   = (const float*)d_in[5];
    const float* b2   = (const float*)d_in[6];
    const float* Wlin = (const float*)d_in[7];
    const float* blin = (const float*)d_in[8];
    float* out = (float*)d_out;

    const int N = in_sizes[2];          // 50000
    const int E = in_sizes[1] / 2;      // 800000
    const int DIN = in_sizes[0] / N;    // 128
    const int B = (N + BSH - 1) / BSH;  // dst buckets (3125)

    // workspace carve-up (256B aligned)
    char* base = (char*)d_ws;
    size_t off = 0;
    auto alloc = [&](size_t bytes) {
        char* p = base + off;
        off = (off + bytes + 255) & ~(size_t)255;
        return p;
    };
    int*   bcnt   = (int*)  alloc((size_t)B * 4);
    int*   bptr   = (int*)  alloc((size_t)(B + 1) * 4);
    int*   bcur   = (int*)  alloc((size_t)B * 4);
    int*   rowptr = (int*)  alloc((size_t)(N + 1) * 4);
    float* dinv   = (float*)alloc((size_t)N * 4);
    int2*  ebuf   = (int2*) alloc((size_t)E * 8);
    int2*  csr    = (int2*) alloc((size_t)E * 8);
    float* h      = (float*)alloc((size_t)N * DH * 4);   // reused for layer-2 pre-agg
    float* x1     = (float*)alloc((size_t)N * DH * 4);
    float* x2     = (float*)alloc((size_t)N * DH * 4);
    float* pool   = (float*)alloc((size_t)NUM_GRAPHS * 128 * 4);
    float* cntf   = (float*)alloc((size_t)NUM_GRAPHS * 4);
    (void)ws_size; (void)n_in; (void)out_size; (void)DIN;

    hipMemsetAsync(bcnt, 0, (size_t)B * 4, stream);
    hipMemsetAsync(pool, 0, (size_t)NUM_GRAPHS * 128 * 4, stream);
    hipMemsetAsync(cntf, 0, (size_t)NUM_GRAPHS * 4, stream);

    // CSR build (bucketed counting sort; shared by both conv layers)
    bcount_kernel<<<(E + 255) / 256, 256, 0, stream>>>(ei, bcnt, E);
    bscan_kernel<<<1, 1024, 0, stream>>>(bcnt, bptr, bcur, B);
    bscatter_kernel<<<(E + 255) / 256, 256, 0, stream>>>(ei, bcur, ebuf, E);
    bnode_kernel<<<B, 256, 0, stream>>>(ebuf, bptr, rowptr, dinv, N, E);
    bfill_kernel<<<B, 256, 0, stream>>>(ebuf, bptr, rowptr, dinv, csr, N);

    // layer 1: 64 rows per block
    gemm_kernel<128><<<(N + 63) / 64, 256, 0, stream>>>(x, W1, h, N);
    agg_kernel<<<(N + 3) / 4, 256, 0, stream>>>(h, csr, rowptr, dinv, b1, x1, N);
    // layer 2 (h buffer reused)
    gemm_kernel<64><<<(N + 63) / 64, 256, 0, stream>>>(x1, W2, h, N);
    agg_kernel<<<(N + 3) / 4, 256, 0, stream>>>(h, csr, rowptr, dinv, b2, x2, N);

    // pooling + head
    const int nodesPerBlock = 32;
    pool_kernel<<<(N + nodesPerBlock - 1) / nodesPerBlock, 128, 0, stream>>>(
        x1, x2, batch, pool, cntf, N, nodesPerBlock);
    final_kernel<<<1, 512, 0, stream>>>(pool, cntf, Wlin, blin, out);
}

// Round 8
// 318.410 us; speedup vs baseline: 1.2713x; 1.2713x over previous
//
#include <hip/hip_runtime.h>

static constexpr int NUM_GRAPHS = 64;
static constexpr int DH = 64;      // hidden dim == wave size
static constexpr int DOUT = 7;

// ---------- CSR build ----------
__global__ void count_kernel(const int* __restrict__ ei, int* __restrict__ deg, int E) {
    int e = blockIdx.x * blockDim.x + threadIdx.x;
    if (e < E) atomicAdd(&deg[ei[E + e]], 1);   // dst row of edge_index
}

// per-block degree sums
__global__ __launch_bounds__(256) void partial_kernel(const int* __restrict__ deg,
                                                      int* __restrict__ bsum, int N) {
    __shared__ int sh[256];
    int t = threadIdx.x;
    int i = blockIdx.x * 256 + t;
    sh[t] = (i < N) ? deg[i] : 0;
    __syncthreads();
    for (int s = 128; s > 0; s >>= 1) {
        if (t < s) sh[t] += sh[t + s];
        __syncthreads();
    }
    if (t == 0) bsum[blockIdx.x] = sh[0];
}

// per-block: offset = sum(bsum[0..b)), then 256-wide LDS scan of this chunk
__global__ __launch_bounds__(256) void emit_kernel(const int* __restrict__ deg,
                                                   const int* __restrict__ bsum,
                                                   int* __restrict__ rowptr,
                                                   int* __restrict__ cursor,
                                                   float* __restrict__ dinv, int N) {
    __shared__ int red[256];
    __shared__ int sh[256];
    int t = threadIdx.x;
    int b = blockIdx.x;
    int i = b * 256 + t;

    int part = 0;
    for (int j = t; j < b; j += 256) part += bsum[j];
    red[t] = part;
    __syncthreads();
    for (int s = 128; s > 0; s >>= 1) {
        if (t < s) red[t] += red[t + s];
        __syncthreads();
    }
    int base = red[0];

    int d = (i < N) ? deg[i] : 0;
    sh[t] = d;
    __syncthreads();
    for (int off = 1; off < 256; off <<= 1) {
        int v = (t >= off) ? sh[t - off] : 0;
        __syncthreads();
        sh[t] += v;
        __syncthreads();
    }
    int excl = sh[t] - d;

    if (i < N) {
        rowptr[i] = base + excl;
        cursor[i] = base + excl;
        dinv[i] = rsqrtf((float)(d + 1));   // +1: self-loop
    }
    if (i == N - 1) rowptr[N] = base + excl + d;
}

__global__ void fill_kernel(const int* __restrict__ ei, int* __restrict__ cursor,
                            const float* __restrict__ dinv, int2* __restrict__ csr, int E) {
    int e = blockIdx.x * blockDim.x + threadIdx.x;
    if (e >= E) return;
    int src = ei[e];
    int dst = ei[E + e];
    int pos = atomicAdd(&cursor[dst], 1);
    float w = dinv[src] * dinv[dst];
    csr[pos] = make_int2(src, __float_as_int(w));
}

// ---------- dense GEMM: h[N,64] = x[N,K] @ W[K,64] ----------
// Block = 256 threads = 4 waves, 64 rows/block. W tile + x tile staged in LDS.
template <int K>
__global__ __launch_bounds__(256) void gemm_kernel(const float* __restrict__ x,
                                                   const float* __restrict__ W,
                                                   float* __restrict__ h, int N) {
    __shared__ float4 sX4[64][K / 4];
    __shared__ float  sW[K][64];
    int t = threadIdx.x;
    int r0 = blockIdx.x * 64;

    const float4* W4 = (const float4*)W;
    for (int v = t; v < K * 16; v += 256) {
        int k = v >> 4, c4 = v & 15;
        *(float4*)&sW[k][c4 * 4] = W4[v];
    }
    for (int v = t; v < 64 * (K / 4); v += 256) {
        int row = v / (K / 4), c4 = v % (K / 4);
        int gr = min(r0 + row, N - 1);
        sX4[row][c4] = *(const float4*)(x + (size_t)gr * K + 4 * c4);
    }
    __syncthreads();

    int c = t & 63;
    int w = t >> 6;
    float acc[16];
#pragma unroll
    for (int r = 0; r < 16; ++r) acc[r] = 0.f;

#pragma unroll 2
    for (int k4 = 0; k4 < K / 4; ++k4) {
        float w0 = sW[4 * k4 + 0][c];
        float w1 = sW[4 * k4 + 1][c];
        float w2 = sW[4 * k4 + 2][c];
        float w3 = sW[4 * k4 + 3][c];
#pragma unroll
        for (int r = 0; r < 16; ++r) {
            float4 xv = sX4[w * 16 + r][k4];    // broadcast
            acc[r] = fmaf(xv.x, w0, acc[r]);
            acc[r] = fmaf(xv.y, w1, acc[r]);
            acc[r] = fmaf(xv.z, w2, acc[r]);
            acc[r] = fmaf(xv.w, w3, acc[r]);
        }
    }

#pragma unroll
    for (int r = 0; r < 16; ++r) {
        int row = r0 + w * 16 + r;
        if (row < N) h[(size_t)row * DH + c] = acc[r];
    }
}

// ---------- sparse aggregation: wave per node, 4 edges per VMEM instr ----------
// lane = (g = lane>>4, s = lane&15): group g handles edge i+g, lane loads
// h[src_g] float4 #s. One wave-wide gather = 4 rows (1KB) vs 1 row before ->
// 2 VMEM instrs per 4 edges instead of 5 (the previous issue-rate limit).
__global__ __launch_bounds__(256) void agg_kernel(const float* __restrict__ h,
                                                  const int2* __restrict__ csr,
                                                  const int* __restrict__ rowptr,
                                                  const float* __restrict__ dinv,
                                                  const float* __restrict__ bias,
                                                  float* __restrict__ out, int N) {
    int lane = threadIdx.x & 63;
    int node = blockIdx.x * (blockDim.x >> 6) + (threadIdx.x >> 6);
    if (node >= N) return;
    int g = lane >> 4;        // edge group 0..3
    int s = lane & 15;        // float4 index within row

    float4 acc0 = {0.f, 0.f, 0.f, 0.f};
    float4 acc1 = {0.f, 0.f, 0.f, 0.f};
    int beg = rowptr[node], end = rowptr[node + 1];
    int i = beg;
    for (; i + 8 <= end; i += 8) {
        int2 ea = csr[i + g];
        int2 eb = csr[i + 4 + g];
        float4 ha = ((const float4*)(h + (size_t)ea.x * DH))[s];
        float4 hb = ((const float4*)(h + (size_t)eb.x * DH))[s];
        float wa = __int_as_float(ea.y);
        float wb = __int_as_float(eb.y);
        acc0.x = fmaf(wa, ha.x, acc0.x); acc0.y = fmaf(wa, ha.y, acc0.y);
        acc0.z = fmaf(wa, ha.z, acc0.z); acc0.w = fmaf(wa, ha.w, acc0.w);
        acc1.x = fmaf(wb, hb.x, acc1.x); acc1.y = fmaf(wb, hb.y, acc1.y);
        acc1.z = fmaf(wb, hb.z, acc1.z); acc1.w = fmaf(wb, hb.w, acc1.w);
    }
    if (i + 4 <= end) {
        int2 ea = csr[i + g];
        float4 ha = ((const float4*)(h + (size_t)ea.x * DH))[s];
        float wa = __int_as_float(ea.y);
        acc0.x = fmaf(wa, ha.x, acc0.x); acc0.y = fmaf(wa, ha.y, acc0.y);
        acc0.z = fmaf(wa, ha.z, acc0.z); acc0.w = fmaf(wa, ha.w, acc0.w);
        i += 4;
    }
    if (i + g < end) {        // remainder 0..3 edges, one per group
        int2 ea = csr[i + g];
        float4 ha = ((const float4*)(h + (size_t)ea.x * DH))[s];
        float wa = __int_as_float(ea.y);
        acc0.x = fmaf(wa, ha.x, acc0.x); acc0.y = fmaf(wa, ha.y, acc0.y);
        acc0.z = fmaf(wa, ha.z, acc0.z); acc0.w = fmaf(wa, ha.w, acc0.w);
    }
    float4 acc;
    acc.x = acc0.x + acc1.x; acc.y = acc0.y + acc1.y;
    acc.z = acc0.z + acc1.z; acc.w = acc0.w + acc1.w;

    // butterfly-reduce across the 4 groups (lanes differing in bits 4,5)
    acc.x += __shfl_xor(acc.x, 16); acc.y += __shfl_xor(acc.y, 16);
    acc.z += __shfl_xor(acc.z, 16); acc.w += __shfl_xor(acc.w, 16);
    acc.x += __shfl_xor(acc.x, 32); acc.y += __shfl_xor(acc.y, 32);
    acc.z += __shfl_xor(acc.z, 32); acc.w += __shfl_xor(acc.w, 32);

    if (g == 0) {
        float di = dinv[node];
        float dd = di * di;
        float4 hv = ((const float4*)(h + (size_t)node * DH))[s];
        float4 bv = ((const float4*)bias)[s];
        float4 o;
        o.x = fmaxf(fmaf(dd, hv.x, acc.x) + bv.x, 0.f);
        o.y = fmaxf(fmaf(dd, hv.y, acc.y) + bv.y, 0.f);
        o.z = fmaxf(fmaf(dd, hv.z, acc.z) + bv.z, 0.f);
        o.w = fmaxf(fmaf(dd, hv.w, acc.w) + bv.w, 0.f);
        ((float4*)(out + (size_t)node * DH))[s] = o;
    }
}

// ---------- mean pool over sorted batch (JK-cat of x1,x2) ----------
__global__ __launch_bounds__(128) void pool_kernel(const float* __restrict__ x1,
                                                   const float* __restrict__ x2,
                                                   const int* __restrict__ batch,
                                                   float* __restrict__ pool,
                                                   float* __restrict__ cntf,
                                                   int N, int nodesPerBlock) {
    int f = threadIdx.x;  // 0..127
    int start = blockIdx.x * nodesPerBlock;
    int end = min(N, start + nodesPerBlock);
    if (start >= end) return;
    int gcur = batch[start];
    float acc = 0.f;
    int c = 0;
    for (int v = start; v < end; ++v) {
        int g = batch[v];               // uniform across block
        if (g != gcur) {
            atomicAdd(&pool[gcur * 128 + f], acc);
            if (f == 0) atomicAdd(&cntf[gcur], (float)c);
            acc = 0.f; c = 0; gcur = g;
        }
        acc += (f < DH) ? x1[(size_t)v * DH + f] : x2[(size_t)v * DH + (f - DH)];
        ++c;
    }
    atomicAdd(&pool[gcur * 128 + f], acc);
    if (f == 0) atomicAdd(&cntf[gcur], (float)c);
}

// ---------- head: (pool/cnt) @ Wlin + blin ----------
__global__ __launch_bounds__(512) void final_kernel(const float* __restrict__ pool,
                                                    const float* __restrict__ cntf,
                                                    const float* __restrict__ Wlin,
                                                    const float* __restrict__ blin,
                                                    float* __restrict__ out) {
    int t = threadIdx.x;
    if (t >= NUM_GRAPHS * DOUT) return;
    int g = t / DOUT, o = t % DOUT;
    float inv = 1.0f / fmaxf(cntf[g], 1.0f);
    float acc = 0.f;
    for (int k = 0; k < 2 * DH; ++k)
        acc = fmaf(pool[g * 128 + k], Wlin[k * DOUT + o], acc);
    out[t] = acc * inv + blin[o];
}

extern "C" void kernel_launch(void* const* d_in, const int* in_sizes, int n_in,
                              void* d_out, int out_size, void* d_ws, size_t ws_size,
                              hipStream_t stream) {
    const float* x    = (const float*)d_in[0];
    const int*   ei   = (const int*)d_in[1];
    const int*   batch= (const int*)d_in[2];
    const float* W1   = (const float*)d_in[3];
    const float* b1   = (const float*)d_in[4];
    const float* W2   = (const float*)d_in[5];
    const float* b2   = (const float*)d_in[6];
    const float* Wlin = (const float*)d_in[7];
    const float* blin = (const float*)d_in[8];
    float* out = (float*)d_out;

    const int N = in_sizes[2];          // 50000
    const int E = in_sizes[1] / 2;      // 800000
    const int DIN = in_sizes[0] / N;    // 128
    const int NB = (N + 255) / 256;     // scan blocks

    // workspace carve-up (256B aligned)
    char* base = (char*)d_ws;
    size_t off = 0;
    auto alloc = [&](size_t bytes) {
        char* p = base + off;
        off = (off + bytes + 255) & ~(size_t)255;
        return p;
    };
    int*   deg    = (int*)  alloc((size_t)N * 4);
    int*   rowptr = (int*)  alloc((size_t)(N + 1) * 4);
    int*   cursor = (int*)  alloc((size_t)N * 4);
    float* dinv   = (float*)alloc((size_t)N * 4);
    int*   bsum   = (int*)  alloc((size_t)NB * 4);
    int2*  csr    = (int2*) alloc((size_t)E * 8);
    float* h      = (float*)alloc((size_t)N * DH * 4);   // reused for layer-2 pre-agg
    float* x1     = (float*)alloc((size_t)N * DH * 4);
    float* x2     = (float*)alloc((size_t)N * DH * 4);
    float* pool   = (float*)alloc((size_t)NUM_GRAPHS * 128 * 4);
    float* cntf   = (float*)alloc((size_t)NUM_GRAPHS * 4);
    (void)ws_size; (void)n_in; (void)out_size; (void)DIN;

    hipMemsetAsync(deg, 0, (size_t)N * 4, stream);
    hipMemsetAsync(pool, 0, (size_t)NUM_GRAPHS * 128 * 4, stream);
    hipMemsetAsync(cntf, 0, (size_t)NUM_GRAPHS * 4, stream);

    // CSR build (shared by both conv layers)
    count_kernel<<<(E + 255) / 256, 256, 0, stream>>>(ei, deg, E);
    partial_kernel<<<NB, 256, 0, stream>>>(deg, bsum, N);
    emit_kernel<<<NB, 256, 0, stream>>>(deg, bsum, rowptr, cursor, dinv, N);
    fill_kernel<<<(E + 255) / 256, 256, 0, stream>>>(ei, cursor, dinv, csr, E);

    // layer 1: 64 rows per block
    gemm_kernel<128><<<(N + 63) / 64, 256, 0, stream>>>(x, W1, h, N);
    agg_kernel<<<(N + 3) / 4, 256, 0, stream>>>(h, csr, rowptr, dinv, b1, x1, N);
    // layer 2 (h buffer reused)
    gemm_kernel<64><<<(N + 63) / 64, 256, 0, stream>>>(x1, W2, h, N);
    agg_kernel<<<(N + 3) / 4, 256, 0, stream>>>(h, csr, rowptr, dinv, b2, x2, N);

    // pooling + head
    const int nodesPerBlock = 32;
    pool_kernel<<<(N + nodesPerBlock - 1) / nodesPerBlock, 128, 0, stream>>>(
        x1, x2, batch, pool, cntf, N, nodesPerBlock);
    final_kernel<<<1, 512, 0, stream>>>(pool, cntf, Wlin, blin, out);
}

// Round 9
// 279.069 us; speedup vs baseline: 1.4505x; 1.1410x over previous
//
#include <hip/hip_runtime.h>

static constexpr int NUM_GRAPHS = 64;
static constexpr int DH = 64;      // hidden dim == wave size
static constexpr int DOUT = 7;
static constexpr int EPB = 8192;   // edges per scatter block
static constexpr int BSH = 8;      // bucket shift: 256 nodes per bucket

// ---------- CSR build: radix partition by dst-bucket, block-private ranges ----------
// 1: per-block histogram over buckets -> hist[bucket][blk] (bucket-major)
__global__ __launch_bounds__(256) void hist_kernel(const int* __restrict__ ei,
                                                   int* __restrict__ hist,
                                                   int E, int NBLK, int NBUCK) {
    __shared__ int lh[256];
    int t = threadIdx.x, blk = blockIdx.x;
    lh[t] = 0;
    __syncthreads();
    int s = blk * EPB, e = min(E, s + EPB);
    for (int i = s + t; i < e; i += 256)
        atomicAdd(&lh[ei[E + i] >> BSH], 1);
    __syncthreads();
    if (t < NBUCK) hist[t * NBLK + blk] = lh[t];
}

// 2a: per-block sums of an int array (generic)
__global__ __launch_bounds__(256) void partial_kernel(const int* __restrict__ in,
                                                      int* __restrict__ bsum, int L) {
    __shared__ int sh[256];
    int t = threadIdx.x;
    int i = blockIdx.x * 256 + t;
    sh[t] = (i < L) ? in[i] : 0;
    __syncthreads();
    for (int s = 128; s > 0; s >>= 1) {
        if (t < s) sh[t] += sh[t + s];
        __syncthreads();
    }
    if (t == 0) bsum[blockIdx.x] = sh[0];
}

// 2b: exclusive scan using per-block sums (generic)
__global__ __launch_bounds__(256) void escan_kernel(const int* __restrict__ in,
                                                    const int* __restrict__ bsum,
                                                    int* __restrict__ offs, int L) {
    __shared__ int red[256];
    __shared__ int sh[256];
    int t = threadIdx.x, b = blockIdx.x, i = b * 256 + t;
    int part = 0;
    for (int j = t; j < b; j += 256) part += bsum[j];
    red[t] = part;
    __syncthreads();
    for (int s = 128; s > 0; s >>= 1) {
        if (t < s) red[t] += red[t + s];
        __syncthreads();
    }
    int base = red[0];
    int d = (i < L) ? in[i] : 0;
    sh[t] = d;
    __syncthreads();
    for (int off = 1; off < 256; off <<= 1) {
        int v = (t >= off) ? sh[t - off] : 0;
        __syncthreads();
        sh[t] += v;
        __syncthreads();
    }
    if (i < L) offs[i] = base + sh[t] - d;
}

// 3: scatter edges into bucket-grouped ebuf; each (block,bucket) sub-range is
// private to this block -> writes are sequential & temporally clustered.
__global__ __launch_bounds__(256) void scatter_kernel(const int* __restrict__ ei,
                                                      const int* __restrict__ offs,
                                                      int2* __restrict__ ebuf,
                                                      int E, int NBLK, int NBUCK) {
    __shared__ int cur[256];
    int t = threadIdx.x, blk = blockIdx.x;
    if (t < NBUCK) cur[t] = offs[t * NBLK + blk];
    __syncthreads();
    int s = blk * EPB, e = min(E, s + EPB);
    for (int i = s + t; i < e; i += 256) {
        int src = ei[i], dst = ei[E + i];
        int p = atomicAdd(&cur[dst >> BSH], 1);
        ebuf[p] = make_int2(src, dst);
    }
}

// 4: per-bucket degree count + LDS scan -> rowptr, dinv (replaces global-atomic deg)
__global__ __launch_bounds__(256) void brow_kernel(const int2* __restrict__ ebuf,
                                                   const int* __restrict__ offs,
                                                   int* __restrict__ rowptr,
                                                   float* __restrict__ dinv,
                                                   int N, int E, int NBLK, int NBUCK) {
    __shared__ int dcnt[256];
    __shared__ int sc[256];
    int t = threadIdx.x, B = blockIdx.x;
    dcnt[t] = 0;
    __syncthreads();
    int beg = offs[B * NBLK];
    int end = (B + 1 < NBUCK) ? offs[(B + 1) * NBLK] : E;
    for (int i = beg + t; i < end; i += 256)
        atomicAdd(&dcnt[ebuf[i].y & 255], 1);
    __syncthreads();
    int d = dcnt[t];
    sc[t] = d;
    __syncthreads();
    for (int off = 1; off < 256; off <<= 1) {
        int v = (t >= off) ? sc[t - off] : 0;
        __syncthreads();
        sc[t] += v;
        __syncthreads();
    }
    int v = B * 256 + t;
    if (v < N) {
        rowptr[v] = beg + sc[t] - d;
        dinv[v] = rsqrtf((float)(d + 1));   // +1: self-loop
    }
    if (B == 0 && t == 0) rowptr[N] = E;
}

// 5: per-bucket CSR fill; csr writes confined to this bucket's contiguous region
__global__ __launch_bounds__(256) void bfill_kernel(const int2* __restrict__ ebuf,
                                                    const int* __restrict__ offs,
                                                    const int* __restrict__ rowptr,
                                                    const float* __restrict__ dinv,
                                                    int2* __restrict__ csr,
                                                    int N, int E, int NBLK, int NBUCK) {
    __shared__ int cur[256];
    __shared__ float sdv[256];
    int t = threadIdx.x, B = blockIdx.x;
    int v = B * 256 + t;
    cur[t] = (v < N) ? rowptr[v] : 0;
    sdv[t] = (v < N) ? dinv[v] : 0.f;
    __syncthreads();
    int beg = offs[B * NBLK];
    int end = (B + 1 < NBUCK) ? offs[(B + 1) * NBLK] : E;
    for (int i = beg + t; i < end; i += 256) {
        int2 ed = ebuf[i];
        int l = ed.y & 255;
        int p = atomicAdd(&cur[l], 1);
        csr[p] = make_int2(ed.x, __float_as_int(dinv[ed.x] * sdv[l]));
    }
}

// ---------- dense GEMM: h[N,64] = x[N,K] @ W[K,64] (LDS-staged) ----------
template <int K>
__global__ __launch_bounds__(256) void gemm_kernel(const float* __restrict__ x,
                                                   const float* __restrict__ W,
                                                   float* __restrict__ h, int N) {
    __shared__ float4 sX4[64][K / 4];
    __shared__ float  sW[K][64];
    int t = threadIdx.x;
    int r0 = blockIdx.x * 64;

    const float4* W4 = (const float4*)W;
    for (int v = t; v < K * 16; v += 256) {
        int k = v >> 4, c4 = v & 15;
        *(float4*)&sW[k][c4 * 4] = W4[v];
    }
    for (int v = t; v < 64 * (K / 4); v += 256) {
        int row = v / (K / 4), c4 = v % (K / 4);
        int gr = min(r0 + row, N - 1);
        sX4[row][c4] = *(const float4*)(x + (size_t)gr * K + 4 * c4);
    }
    __syncthreads();

    int c = t & 63;
    int w = t >> 6;
    float acc[16];
#pragma unroll
    for (int r = 0; r < 16; ++r) acc[r] = 0.f;

#pragma unroll 2
    for (int k4 = 0; k4 < K / 4; ++k4) {
        float w0 = sW[4 * k4 + 0][c];
        float w1 = sW[4 * k4 + 1][c];
        float w2 = sW[4 * k4 + 2][c];
        float w3 = sW[4 * k4 + 3][c];
#pragma unroll
        for (int r = 0; r < 16; ++r) {
            float4 xv = sX4[w * 16 + r][k4];    // broadcast
            acc[r] = fmaf(xv.x, w0, acc[r]);
            acc[r] = fmaf(xv.y, w1, acc[r]);
            acc[r] = fmaf(xv.z, w2, acc[r]);
            acc[r] = fmaf(xv.w, w3, acc[r]);
        }
    }

#pragma unroll
    for (int r = 0; r < 16; ++r) {
        int row = r0 + w * 16 + r;
        if (row < N) h[(size_t)row * DH + c] = acc[r];
    }
}

// ---------- sparse aggregation: wave per node, 4 edges per VMEM instr ----------
__global__ __launch_bounds__(256) void agg_kernel(const float* __restrict__ h,
                                                  const int2* __restrict__ csr,
                                                  const int* __restrict__ rowptr,
                                                  const float* __restrict__ dinv,
                                                  const float* __restrict__ bias,
                                                  float* __restrict__ out, int N) {
    int lane = threadIdx.x & 63;
    int node = blockIdx.x * (blockDim.x >> 6) + (threadIdx.x >> 6);
    if (node >= N) return;
    int g = lane >> 4;        // edge group 0..3
    int s = lane & 15;        // float4 index within row

    float4 acc0 = {0.f, 0.f, 0.f, 0.f};
    float4 acc1 = {0.f, 0.f, 0.f, 0.f};
    int beg = rowptr[node], end = rowptr[node + 1];
    int i = beg;
    for (; i + 8 <= end; i += 8) {
        int2 ea = csr[i + g];
        int2 eb = csr[i + 4 + g];
        float4 ha = ((const float4*)(h + (size_t)ea.x * DH))[s];
        float4 hb = ((const float4*)(h + (size_t)eb.x * DH))[s];
        float wa = __int_as_float(ea.y);
        float wb = __int_as_float(eb.y);
        acc0.x = fmaf(wa, ha.x, acc0.x); acc0.y = fmaf(wa, ha.y, acc0.y);
        acc0.z = fmaf(wa, ha.z, acc0.z); acc0.w = fmaf(wa, ha.w, acc0.w);
        acc1.x = fmaf(wb, hb.x, acc1.x); acc1.y = fmaf(wb, hb.y, acc1.y);
        acc1.z = fmaf(wb, hb.z, acc1.z); acc1.w = fmaf(wb, hb.w, acc1.w);
    }
    if (i + 4 <= end) {
        int2 ea = csr[i + g];
        float4 ha = ((const float4*)(h + (size_t)ea.x * DH))[s];
        float wa = __int_as_float(ea.y);
        acc0.x = fmaf(wa, ha.x, acc0.x); acc0.y = fmaf(wa, ha.y, acc0.y);
        acc0.z = fmaf(wa, ha.z, acc0.z); acc0.w = fmaf(wa, ha.w, acc0.w);
        i += 4;
    }
    if (i + g < end) {        // remainder 0..3 edges, one per group
        int2 ea = csr[i + g];
        float4 ha = ((const float4*)(h + (size_t)ea.x * DH))[s];
        float wa = __int_as_float(ea.y);
        acc0.x = fmaf(wa, ha.x, acc0.x); acc0.y = fmaf(wa, ha.y, acc0.y);
        acc0.z = fmaf(wa, ha.z, acc0.z); acc0.w = fmaf(wa, ha.w, acc0.w);
    }
    float4 acc;
    acc.x = acc0.x + acc1.x; acc.y = acc0.y + acc1.y;
    acc.z = acc0.z + acc1.z; acc.w = acc0.w + acc1.w;

    // butterfly-reduce across the 4 groups (lanes differing in bits 4,5)
    acc.x += __shfl_xor(acc.x, 16); acc.y += __shfl_xor(acc.y, 16);
    acc.z += __shfl_xor(acc.z, 16); acc.w += __shfl_xor(acc.w, 16);
    acc.x += __shfl_xor(acc.x, 32); acc.y += __shfl_xor(acc.y, 32);
    acc.z += __shfl_xor(acc.z, 32); acc.w += __shfl_xor(acc.w, 32);

    if (g == 0) {
        float di = dinv[node];
        float dd = di * di;
        float4 hv = ((const float4*)(h + (size_t)node * DH))[s];
        float4 bv = ((const float4*)bias)[s];
        float4 o;
        o.x = fmaxf(fmaf(dd, hv.x, acc.x) + bv.x, 0.f);
        o.y = fmaxf(fmaf(dd, hv.y, acc.y) + bv.y, 0.f);
        o.z = fmaxf(fmaf(dd, hv.z, acc.z) + bv.z, 0.f);
        o.w = fmaxf(fmaf(dd, hv.w, acc.w) + bv.w, 0.f);
        ((float4*)(out + (size_t)node * DH))[s] = o;
    }
}

// ---------- mean pool over sorted batch (JK-cat of x1,x2) ----------
__global__ __launch_bounds__(128) void pool_kernel(const float* __restrict__ x1,
                                                   const float* __restrict__ x2,
                                                   const int* __restrict__ batch,
                                                   float* __restrict__ pool,
                                                   float* __restrict__ cntf,
                                                   int N, int nodesPerBlock) {
    int f = threadIdx.x;  // 0..127
    int start = blockIdx.x * nodesPerBlock;
    int end = min(N, start + nodesPerBlock);
    if (start >= end) return;
    int gcur = batch[start];
    float acc = 0.f;
    int c = 0;
    for (int v = start; v < end; ++v) {
        int g = batch[v];               // uniform across block
        if (g != gcur) {
            atomicAdd(&pool[gcur * 128 + f], acc);
            if (f == 0) atomicAdd(&cntf[gcur], (float)c);
            acc = 0.f; c = 0; gcur = g;
        }
        acc += (f < DH) ? x1[(size_t)v * DH + f] : x2[(size_t)v * DH + (f - DH)];
        ++c;
    }
    atomicAdd(&pool[gcur * 128 + f], acc);
    if (f == 0) atomicAdd(&cntf[gcur], (float)c);
}

// ---------- head: (pool/cnt) @ Wlin + blin ----------
__global__ __launch_bounds__(512) void final_kernel(const float* __restrict__ pool,
                                                    const float* __restrict__ cntf,
                                                    const float* __restrict__ Wlin,
                                                    const float* __restrict__ blin,
                                                    float* __restrict__ out) {
    int t = threadIdx.x;
    if (t >= NUM_GRAPHS * DOUT) return;
    int g = t / DOUT, o = t % DOUT;
    float inv = 1.0f / fmaxf(cntf[g], 1.0f);
    float acc = 0.f;
    for (int k = 0; k < 2 * DH; ++k)
        acc = fmaf(pool[g * 128 + k], Wlin[k * DOUT + o], acc);
    out[t] = acc * inv + blin[o];
}

extern "C" void kernel_launch(void* const* d_in, const int* in_sizes, int n_in,
                              void* d_out, int out_size, void* d_ws, size_t ws_size,
                              hipStream_t stream) {
    const float* x    = (const float*)d_in[0];
    const int*   ei   = (const int*)d_in[1];
    const int*   batch= (const int*)d_in[2];
    const float* W1   = (const float*)d_in[3];
    const float* b1   = (const float*)d_in[4];
    const float* W2   = (const float*)d_in[5];
    const float* b2   = (const float*)d_in[6];
    const float* Wlin = (const float*)d_in[7];
    const float* blin = (const float*)d_in[8];
    float* out = (float*)d_out;

    const int N = in_sizes[2];            // 50000
    const int E = in_sizes[1] / 2;        // 800000
    const int DIN = in_sizes[0] / N;      // 128
    const int NBUCK = (N + 255) >> BSH;   // 196 buckets of 256 nodes
    const int NBLK = (E + EPB - 1) / EPB; // 98 scatter blocks
    const int L = NBUCK * NBLK;           // hist length (~19.2K)
    const int LB = (L + 255) / 256;       // scan blocks for hist

    // workspace carve-up (256B aligned)
    char* base = (char*)d_ws;
    size_t off = 0;
    auto alloc = [&](size_t bytes) {
        char* p = base + off;
        off = (off + bytes + 255) & ~(size_t)255;
        return p;
    };
    int*   hist   = (int*)  alloc((size_t)L * 4);
    int*   offs   = (int*)  alloc((size_t)L * 4);
    int*   bsum   = (int*)  alloc((size_t)LB * 4);
    int*   rowptr = (int*)  alloc((size_t)(N + 1) * 4);
    float* dinv   = (float*)alloc((size_t)N * 4);
    int2*  ebuf   = (int2*) alloc((size_t)E * 8);
    int2*  csr    = (int2*) alloc((size_t)E * 8);
    float* h      = (float*)alloc((size_t)N * DH * 4);   // reused for layer-2 pre-agg
    float* x1     = (float*)alloc((size_t)N * DH * 4);
    float* x2     = (float*)alloc((size_t)N * DH * 4);
    float* pool   = (float*)alloc((size_t)NUM_GRAPHS * 128 * 4);
    float* cntf   = (float*)alloc((size_t)NUM_GRAPHS * 4);
    (void)ws_size; (void)n_in; (void)out_size; (void)DIN;

    hipMemsetAsync(pool, 0, (size_t)NUM_GRAPHS * 128 * 4, stream);
    hipMemsetAsync(cntf, 0, (size_t)NUM_GRAPHS * 4, stream);

    // CSR build: radix partition (block-private write ranges -> line-local writes)
    hist_kernel<<<NBLK, 256, 0, stream>>>(ei, hist, E, NBLK, NBUCK);
    partial_kernel<<<LB, 256, 0, stream>>>(hist, bsum, L);
    escan_kernel<<<LB, 256, 0, stream>>>(hist, bsum, offs, L);
    scatter_kernel<<<NBLK, 256, 0, stream>>>(ei, offs, ebuf, E, NBLK, NBUCK);
    brow_kernel<<<NBUCK, 256, 0, stream>>>(ebuf, offs, rowptr, dinv, N, E, NBLK, NBUCK);
    bfill_kernel<<<NBUCK, 256, 0, stream>>>(ebuf, offs, rowptr, dinv, csr, N, E, NBLK, NBUCK);

    // layer 1: 64 rows per block
    gemm_kernel<128><<<(N + 63) / 64, 256, 0, stream>>>(x, W1, h, N);
    agg_kernel<<<(N + 3) / 4, 256, 0, stream>>>(h, csr, rowptr, dinv, b1, x1, N);
    // layer 2 (h buffer reused)
    gemm_kernel<64><<<(N + 63) / 64, 256, 0, stream>>>(x1, W2, h, N);
    agg_kernel<<<(N + 3) / 4, 256, 0, stream>>>(h, csr, rowptr, dinv, b2, x2, N);

    // pooling + head
    const int nodesPerBlock = 32;
    pool_kernel<<<(N + nodesPerBlock - 1) / nodesPerBlock, 128, 0, stream>>>(
        x1, x2, batch, pool, cntf, N, nodesPerBlock);
    final_kernel<<<1, 512, 0, stream>>>(pool, cntf, Wlin, blin, out);
}

// Round 10
// 276.807 us; speedup vs baseline: 1.4624x; 1.0082x over previous
//
#include <hip/hip_runtime.h>

static constexpr int NUM_GRAPHS = 64;
static constexpr int DH = 64;      // hidden dim == wave size
static constexpr int DOUT = 7;
static constexpr int EPB = 8192;   // edges per scatter block
static constexpr int BSH = 8;      // bucket shift: 256 nodes per bucket

// ---------- CSR build: radix partition by dst-bucket, block-private ranges ----------
// 1: per-block histogram over buckets -> hist[bucket][blk] (bucket-major)
__global__ __launch_bounds__(256) void hist_kernel(const int* __restrict__ ei,
                                                   int* __restrict__ hist,
                                                   int E, int NBLK, int NBUCK) {
    __shared__ int lh[256];
    int t = threadIdx.x, blk = blockIdx.x;
    lh[t] = 0;
    __syncthreads();
    int s = blk * EPB, e = min(E, s + EPB);
    for (int i = s + t; i < e; i += 256)
        atomicAdd(&lh[ei[E + i] >> BSH], 1);
    __syncthreads();
    if (t < NBUCK) hist[t * NBLK + blk] = lh[t];
}

// 2a: per-block sums of an int array (generic)
__global__ __launch_bounds__(256) void partial_kernel(const int* __restrict__ in,
                                                      int* __restrict__ bsum, int L) {
    __shared__ int sh[256];
    int t = threadIdx.x;
    int i = blockIdx.x * 256 + t;
    sh[t] = (i < L) ? in[i] : 0;
    __syncthreads();
    for (int s = 128; s > 0; s >>= 1) {
        if (t < s) sh[t] += sh[t + s];
        __syncthreads();
    }
    if (t == 0) bsum[blockIdx.x] = sh[0];
}

// 2b: exclusive scan using per-block sums (generic)
__global__ __launch_bounds__(256) void escan_kernel(const int* __restrict__ in,
                                                    const int* __restrict__ bsum,
                                                    int* __restrict__ offs, int L) {
    __shared__ int red[256];
    __shared__ int sh[256];
    int t = threadIdx.x, b = blockIdx.x, i = b * 256 + t;
    int part = 0;
    for (int j = t; j < b; j += 256) part += bsum[j];
    red[t] = part;
    __syncthreads();
    for (int s = 128; s > 0; s >>= 1) {
        if (t < s) red[t] += red[t + s];
        __syncthreads();
    }
    int base = red[0];
    int d = (i < L) ? in[i] : 0;
    sh[t] = d;
    __syncthreads();
    for (int off = 1; off < 256; off <<= 1) {
        int v = (t >= off) ? sh[t - off] : 0;
        __syncthreads();
        sh[t] += v;
        __syncthreads();
    }
    if (i < L) offs[i] = base + sh[t] - d;
}

// 3: scatter edges into bucket-grouped ebuf; each (block,bucket) sub-range is
// private to this block -> writes are sequential & temporally clustered.
__global__ __launch_bounds__(256) void scatter_kernel(const int* __restrict__ ei,
                                                      const int* __restrict__ offs,
                                                      int2* __restrict__ ebuf,
                                                      int E, int NBLK, int NBUCK) {
    __shared__ int cur[256];
    int t = threadIdx.x, blk = blockIdx.x;
    if (t < NBUCK) cur[t] = offs[t * NBLK + blk];
    __syncthreads();
    int s = blk * EPB, e = min(E, s + EPB);
    for (int i = s + t; i < e; i += 256) {
        int src = ei[i], dst = ei[E + i];
        int p = atomicAdd(&cur[dst >> BSH], 1);
        ebuf[p] = make_int2(src, dst);
    }
}

// 4: per-bucket degree count + LDS scan -> rowptr (csr incl. self-loops), dinv
__global__ __launch_bounds__(256) void brow_kernel(const int2* __restrict__ ebuf,
                                                   const int* __restrict__ offs,
                                                   int* __restrict__ rowptr,
                                                   float* __restrict__ dinv,
                                                   int N, int E, int NBLK, int NBUCK) {
    __shared__ int dcnt[256];
    __shared__ int sc[256];
    int t = threadIdx.x, B = blockIdx.x;
    dcnt[t] = 0;
    __syncthreads();
    int beg = offs[B * NBLK];
    int end = (B + 1 < NBUCK) ? offs[(B + 1) * NBLK] : E;
    for (int i = beg + t; i < end; i += 256)
        atomicAdd(&dcnt[ebuf[i].y & 255], 1);
    __syncthreads();
    int v = B * 256 + t;
    int d = (v < N) ? dcnt[t] + 1 : 0;     // +1: self-loop slot in csr
    sc[t] = d;
    __syncthreads();
    for (int off = 1; off < 256; off <<= 1) {
        int vv = (t >= off) ? sc[t - off] : 0;
        __syncthreads();
        sc[t] += vv;
        __syncthreads();
    }
    int base = beg + B * 256;              // bucket's csr start (self slots of prior buckets)
    if (v < N) {
        rowptr[v] = base + sc[t] - d;
        dinv[v] = rsqrtf((float)(dcnt[t] + 1));
    }
    if (B == 0 && t == 0) rowptr[N] = E + N;
}

// 5: per-bucket CSR fill; writes self-edge (v, dinv^2) first, then real edges.
__global__ __launch_bounds__(256) void bfill_kernel(const int2* __restrict__ ebuf,
                                                    const int* __restrict__ offs,
                                                    const int* __restrict__ rowptr,
                                                    const float* __restrict__ dinv,
                                                    int2* __restrict__ csr,
                                                    int N, int E, int NBLK, int NBUCK) {
    __shared__ int cur[256];
    __shared__ float sdv[256];
    int t = threadIdx.x, B = blockIdx.x;
    int v = B * 256 + t;
    if (v < N) {
        int p = rowptr[v];
        float dv = dinv[v];
        csr[p] = make_int2(v, __float_as_int(dv * dv));   // self-loop
        cur[t] = p + 1;
        sdv[t] = dv;
    } else {
        cur[t] = 0;
        sdv[t] = 0.f;
    }
    __syncthreads();
    int beg = offs[B * NBLK];
    int end = (B + 1 < NBUCK) ? offs[(B + 1) * NBLK] : E;
    for (int i = beg + t; i < end; i += 256) {
        int2 ed = ebuf[i];
        int l = ed.y & 255;
        int p = atomicAdd(&cur[l], 1);
        csr[p] = make_int2(ed.x, __float_as_int(dinv[ed.x] * sdv[l]));
    }
}

// ---------- dense GEMM: h[N,64] = x[N,K] @ W[K,64] (LDS-staged) ----------
template <int K>
__global__ __launch_bounds__(256) void gemm_kernel(const float* __restrict__ x,
                                                   const float* __restrict__ W,
                                                   float* __restrict__ h, int N) {
    __shared__ float4 sX4[64][K / 4];
    __shared__ float  sW[K][64];
    int t = threadIdx.x;
    int r0 = blockIdx.x * 64;

    const float4* W4 = (const float4*)W;
    for (int v = t; v < K * 16; v += 256) {
        int k = v >> 4, c4 = v & 15;
        *(float4*)&sW[k][c4 * 4] = W4[v];
    }
    for (int v = t; v < 64 * (K / 4); v += 256) {
        int row = v / (K / 4), c4 = v % (K / 4);
        int gr = min(r0 + row, N - 1);
        sX4[row][c4] = *(const float4*)(x + (size_t)gr * K + 4 * c4);
    }
    __syncthreads();

    int c = t & 63;
    int w = t >> 6;
    float acc[16];
#pragma unroll
    for (int r = 0; r < 16; ++r) acc[r] = 0.f;

#pragma unroll 2
    for (int k4 = 0; k4 < K / 4; ++k4) {
        float w0 = sW[4 * k4 + 0][c];
        float w1 = sW[4 * k4 + 1][c];
        float w2 = sW[4 * k4 + 2][c];
        float w3 = sW[4 * k4 + 3][c];
#pragma unroll
        for (int r = 0; r < 16; ++r) {
            float4 xv = sX4[w * 16 + r][k4];    // broadcast
            acc[r] = fmaf(xv.x, w0, acc[r]);
            acc[r] = fmaf(xv.y, w1, acc[r]);
            acc[r] = fmaf(xv.z, w2, acc[r]);
            acc[r] = fmaf(xv.w, w3, acc[r]);
        }
    }

#pragma unroll
    for (int r = 0; r < 16; ++r) {
        int row = r0 + w * 16 + r;
        if (row < N) h[(size_t)row * DH + c] = acc[r];
    }
}

// ---------- sparse aggregation: wave per node, 4 edges per VMEM instr ----------
// CSR rows include the self-loop, so the loop is uniform; unroll x16 keeps
// 4 csr loads + 4 row gathers in flight.
__global__ __launch_bounds__(256) void agg_kernel(const float* __restrict__ h,
                                                  const int2* __restrict__ csr,
                                                  const int* __restrict__ rowptr,
                                                  const float* __restrict__ bias,
                                                  float* __restrict__ out, int N) {
    int lane = threadIdx.x & 63;
    int node = blockIdx.x * (blockDim.x >> 6) + (threadIdx.x >> 6);
    if (node >= N) return;
    int g = lane >> 4;        // edge group 0..3
    int s = lane & 15;        // float4 index within row

    float4 acc0 = {0.f, 0.f, 0.f, 0.f};
    float4 acc1 = {0.f, 0.f, 0.f, 0.f};
    float4 acc2 = {0.f, 0.f, 0.f, 0.f};
    float4 acc3 = {0.f, 0.f, 0.f, 0.f};
    int beg = rowptr[node], end = rowptr[node + 1];
    int i = beg;
    for (; i + 16 <= end; i += 16) {
        int2 ea = csr[i + g];
        int2 eb = csr[i + 4 + g];
        int2 ec = csr[i + 8 + g];
        int2 ed = csr[i + 12 + g];
        float4 ha = ((const float4*)(h + (size_t)ea.x * DH))[s];
        float4 hb = ((const float4*)(h + (size_t)eb.x * DH))[s];
        float4 hc = ((const float4*)(h + (size_t)ec.x * DH))[s];
        float4 hd = ((const float4*)(h + (size_t)ed.x * DH))[s];
        float wa = __int_as_float(ea.y), wb = __int_as_float(eb.y);
        float wc = __int_as_float(ec.y), wd = __int_as_float(ed.y);
        acc0.x = fmaf(wa, ha.x, acc0.x); acc0.y = fmaf(wa, ha.y, acc0.y);
        acc0.z = fmaf(wa, ha.z, acc0.z); acc0.w = fmaf(wa, ha.w, acc0.w);
        acc1.x = fmaf(wb, hb.x, acc1.x); acc1.y = fmaf(wb, hb.y, acc1.y);
        acc1.z = fmaf(wb, hb.z, acc1.z); acc1.w = fmaf(wb, hb.w, acc1.w);
        acc2.x = fmaf(wc, hc.x, acc2.x); acc2.y = fmaf(wc, hc.y, acc2.y);
        acc2.z = fmaf(wc, hc.z, acc2.z); acc2.w = fmaf(wc, hc.w, acc2.w);
        acc3.x = fmaf(wd, hd.x, acc3.x); acc3.y = fmaf(wd, hd.y, acc3.y);
        acc3.z = fmaf(wd, hd.z, acc3.z); acc3.w = fmaf(wd, hd.w, acc3.w);
    }
    for (; i + 8 <= end; i += 8) {
        int2 ea = csr[i + g];
        int2 eb = csr[i + 4 + g];
        float4 ha = ((const float4*)(h + (size_t)ea.x * DH))[s];
        float4 hb = ((const float4*)(h + (size_t)eb.x * DH))[s];
        float wa = __int_as_float(ea.y), wb = __int_as_float(eb.y);
        acc0.x = fmaf(wa, ha.x, acc0.x); acc0.y = fmaf(wa, ha.y, acc0.y);
        acc0.z = fmaf(wa, ha.z, acc0.z); acc0.w = fmaf(wa, ha.w, acc0.w);
        acc1.x = fmaf(wb, hb.x, acc1.x); acc1.y = fmaf(wb, hb.y, acc1.y);
        acc1.z = fmaf(wb, hb.z, acc1.z); acc1.w = fmaf(wb, hb.w, acc1.w);
    }
    if (i + 4 <= end) {
        int2 ea = csr[i + g];
        float4 ha = ((const float4*)(h + (size_t)ea.x * DH))[s];
        float wa = __int_as_float(ea.y);
        acc0.x = fmaf(wa, ha.x, acc0.x); acc0.y = fmaf(wa, ha.y, acc0.y);
        acc0.z = fmaf(wa, ha.z, acc0.z); acc0.w = fmaf(wa, ha.w, acc0.w);
        i += 4;
    }
    if (i + g < end) {        // remainder 0..3 edges, one per group
        int2 ea = csr[i + g];
        float4 ha = ((const float4*)(h + (size_t)ea.x * DH))[s];
        float wa = __int_as_float(ea.y);
        acc2.x = fmaf(wa, ha.x, acc2.x); acc2.y = fmaf(wa, ha.y, acc2.y);
        acc2.z = fmaf(wa, ha.z, acc2.z); acc2.w = fmaf(wa, ha.w, acc2.w);
    }
    float4 acc;
    acc.x = (acc0.x + acc1.x) + (acc2.x + acc3.x);
    acc.y = (acc0.y + acc1.y) + (acc2.y + acc3.y);
    acc.z = (acc0.z + acc1.z) + (acc2.z + acc3.z);
    acc.w = (acc0.w + acc1.w) + (acc2.w + acc3.w);

    // butterfly-reduce across the 4 groups (lanes differing in bits 4,5)
    acc.x += __shfl_xor(acc.x, 16); acc.y += __shfl_xor(acc.y, 16);
    acc.z += __shfl_xor(acc.z, 16); acc.w += __shfl_xor(acc.w, 16);
    acc.x += __shfl_xor(acc.x, 32); acc.y += __shfl_xor(acc.y, 32);
    acc.z += __shfl_xor(acc.z, 32); acc.w += __shfl_xor(acc.w, 32);

    if (g == 0) {
        float4 bv = ((const float4*)bias)[s];
        float4 o;
        o.x = fmaxf(acc.x + bv.x, 0.f);
        o.y = fmaxf(acc.y + bv.y, 0.f);
        o.z = fmaxf(acc.z + bv.z, 0.f);
        o.w = fmaxf(acc.w + bv.w, 0.f);
        ((float4*)(out + (size_t)node * DH))[s] = o;
    }
}

// ---------- mean pool over sorted batch (JK-cat of x1,x2) ----------
__global__ __launch_bounds__(128) void pool_kernel(const float* __restrict__ x1,
                                                   const float* __restrict__ x2,
                                                   const int* __restrict__ batch,
                                                   float* __restrict__ pool,
                                                   float* __restrict__ cntf,
                                                   int N, int nodesPerBlock) {
    int f = threadIdx.x;  // 0..127
    int start = blockIdx.x * nodesPerBlock;
    int end = min(N, start + nodesPerBlock);
    if (start >= end) return;
    int gcur = batch[start];
    float acc = 0.f;
    int c = 0;
    for (int v = start; v < end; ++v) {
        int g = batch[v];               // uniform across block
        if (g != gcur) {
            atomicAdd(&pool[gcur * 128 + f], acc);
            if (f == 0) atomicAdd(&cntf[gcur], (float)c);
            acc = 0.f; c = 0; gcur = g;
        }
        acc += (f < DH) ? x1[(size_t)v * DH + f] : x2[(size_t)v * DH + (f - DH)];
        ++c;
    }
    atomicAdd(&pool[gcur * 128 + f], acc);
    if (f == 0) atomicAdd(&cntf[gcur], (float)c);
}

// ---------- head: (pool/cnt) @ Wlin + blin ----------
__global__ __launch_bounds__(512) void final_kernel(const float* __restrict__ pool,
                                                    const float* __restrict__ cntf,
                                                    const float* __restrict__ Wlin,
                                                    const float* __restrict__ blin,
                                                    float* __restrict__ out) {
    int t = threadIdx.x;
    if (t >= NUM_GRAPHS * DOUT) return;
    int g = t / DOUT, o = t % DOUT;
    float inv = 1.0f / fmaxf(cntf[g], 1.0f);
    float acc = 0.f;
    for (int k = 0; k < 2 * DH; ++k)
        acc = fmaf(pool[g * 128 + k], Wlin[k * DOUT + o], acc);
    out[t] = acc * inv + blin[o];
}

extern "C" void kernel_launch(void* const* d_in, const int* in_sizes, int n_in,
                              void* d_out, int out_size, void* d_ws, size_t ws_size,
                              hipStream_t stream) {
    const float* x    = (const float*)d_in[0];
    const int*   ei   = (const int*)d_in[1];
    const int*   batch= (const int*)d_in[2];
    const float* W1   = (const float*)d_in[3];
    const float* b1   = (const float*)d_in[4];
    const float* W2   = (const float*)d_in[5];
    const float* b2   = (const float*)d_in[6];
    const float* Wlin = (const float*)d_in[7];
    const float* blin = (const float*)d_in[8];
    float* out = (float*)d_out;

    const int N = in_sizes[2];            // 50000
    const int E = in_sizes[1] / 2;        // 800000
    const int DIN = in_sizes[0] / N;      // 128
    const int NBUCK = (N + 255) >> BSH;   // 196 buckets of 256 nodes
    const int NBLK = (E + EPB - 1) / EPB; // 98 scatter blocks
    const int L = NBUCK * NBLK;           // hist length (~19.2K)
    const int LB = (L + 255) / 256;       // scan blocks for hist

    // workspace carve-up (256B aligned)
    char* base = (char*)d_ws;
    size_t off = 0;
    auto alloc = [&](size_t bytes) {
        char* p = base + off;
        off = (off + bytes + 255) & ~(size_t)255;
        return p;
    };
    int*   hist   = (int*)  alloc((size_t)L * 4);
    int*   offs   = (int*)  alloc((size_t)L * 4);
    int*   bsum   = (int*)  alloc((size_t)LB * 4);
    int*   rowptr = (int*)  alloc((size_t)(N + 1) * 4);
    float* dinv   = (float*)alloc((size_t)N * 4);
    int2*  ebuf   = (int2*) alloc((size_t)E * 8);
    int2*  csr    = (int2*) alloc((size_t)(E + N) * 8);   // + self-loops
    float* h      = (float*)alloc((size_t)N * DH * 4);    // reused for layer-2 pre-agg
    float* x1     = (float*)alloc((size_t)N * DH * 4);
    float* x2     = (float*)alloc((size_t)N * DH * 4);
    float* pool   = (float*)alloc((size_t)NUM_GRAPHS * 128 * 4);
    float* cntf   = (float*)alloc((size_t)NUM_GRAPHS * 4);
    (void)ws_size; (void)n_in; (void)out_size; (void)DIN;

    hipMemsetAsync(pool, 0, (size_t)NUM_GRAPHS * 128 * 4, stream);
    hipMemsetAsync(cntf, 0, (size_t)NUM_GRAPHS * 4, stream);

    // CSR build: radix partition (block-private write ranges -> line-local writes)
    hist_kernel<<<NBLK, 256, 0, stream>>>(ei, hist, E, NBLK, NBUCK);
    partial_kernel<<<LB, 256, 0, stream>>>(hist, bsum, L);
    escan_kernel<<<LB, 256, 0, stream>>>(hist, bsum, offs, L);
    scatter_kernel<<<NBLK, 256, 0, stream>>>(ei, offs, ebuf, E, NBLK, NBUCK);
    brow_kernel<<<NBUCK, 256, 0, stream>>>(ebuf, offs, rowptr, dinv, N, E, NBLK, NBUCK);
    bfill_kernel<<<NBUCK, 256, 0, stream>>>(ebuf, offs, rowptr, dinv, csr, N, E, NBLK, NBUCK);

    // layer 1: 64 rows per block
    gemm_kernel<128><<<(N + 63) / 64, 256, 0, stream>>>(x, W1, h, N);
    agg_kernel<<<(N + 3) / 4, 256, 0, stream>>>(h, csr, rowptr, b1, x1, N);
    // layer 2 (h buffer reused)
    gemm_kernel<64><<<(N + 63) / 64, 256, 0, stream>>>(x1, W2, h, N);
    agg_kernel<<<(N + 3) / 4, 256, 0, stream>>>(h, csr, rowptr, b2, x2, N);

    // pooling + head
    const int nodesPerBlock = 32;
    pool_kernel<<<(N + nodesPerBlock - 1) / nodesPerBlock, 128, 0, stream>>>(
        x1, x2, batch, pool, cntf, N, nodesPerBlock);
    final_kernel<<<1, 512, 0, stream>>>(pool, cntf, Wlin, blin, out);
}

// Round 11
// 271.570 us; speedup vs baseline: 1.4906x; 1.0193x over previous
//
#include <hip/hip_runtime.h>

static constexpr int NUM_GRAPHS = 64;
static constexpr int DH = 64;      // hidden dim == wave size
static constexpr int DOUT = 7;
static constexpr int EPB = 8192;   // edges per scatter block
static constexpr int BSH = 8;      // bucket shift: 256 nodes per bucket
static constexpr int LDSCAP = 8192; // max edges cached in LDS per bucket

// ---------- CSR build: radix partition by dst-bucket, block-private ranges ----------
// Edge payload is packed: (src << 8) | (dst & 255). Weights are factored out:
// gemm pre-scales rows by dinv[src], agg post-scales by dinv[dst].

// 1: per-block histogram over buckets -> hist[bucket][blk] (bucket-major)
__global__ __launch_bounds__(256) void hist_kernel(const int* __restrict__ ei,
                                                   int* __restrict__ hist,
                                                   int E, int NBLK, int NBUCK) {
    __shared__ int lh[256];
    int t = threadIdx.x, blk = blockIdx.x;
    lh[t] = 0;
    __syncthreads();
    int s = blk * EPB, e = min(E, s + EPB);
    for (int i = s + t; i < e; i += 256)
        atomicAdd(&lh[ei[E + i] >> BSH], 1);
    __syncthreads();
    if (t < NBUCK) hist[t * NBLK + blk] = lh[t];
}

// 2a: per-block sums of an int array (generic)
__global__ __launch_bounds__(256) void partial_kernel(const int* __restrict__ in,
                                                      int* __restrict__ bsum, int L) {
    __shared__ int sh[256];
    int t = threadIdx.x;
    int i = blockIdx.x * 256 + t;
    sh[t] = (i < L) ? in[i] : 0;
    __syncthreads();
    for (int s = 128; s > 0; s >>= 1) {
        if (t < s) sh[t] += sh[t + s];
        __syncthreads();
    }
    if (t == 0) bsum[blockIdx.x] = sh[0];
}

// 2b: exclusive scan using per-block sums (generic)
__global__ __launch_bounds__(256) void escan_kernel(const int* __restrict__ in,
                                                    const int* __restrict__ bsum,
                                                    int* __restrict__ offs, int L) {
    __shared__ int red[256];
    __shared__ int sh[256];
    int t = threadIdx.x, b = blockIdx.x, i = b * 256 + t;
    int part = 0;
    for (int j = t; j < b; j += 256) part += bsum[j];
    red[t] = part;
    __syncthreads();
    for (int s = 128; s > 0; s >>= 1) {
        if (t < s) red[t] += red[t + s];
        __syncthreads();
    }
    int base = red[0];
    int d = (i < L) ? in[i] : 0;
    sh[t] = d;
    __syncthreads();
    for (int off = 1; off < 256; off <<= 1) {
        int v = (t >= off) ? sh[t - off] : 0;
        __syncthreads();
        sh[t] += v;
        __syncthreads();
    }
    if (i < L) offs[i] = base + sh[t] - d;
}

// 3: scatter packed edges into bucket-grouped ebuf (block-private sub-ranges)
__global__ __launch_bounds__(256) void scatter_kernel(const int* __restrict__ ei,
                                                      const int* __restrict__ offs,
                                                      int* __restrict__ ebuf,
                                                      int E, int NBLK, int NBUCK) {
    __shared__ int cur[256];
    int t = threadIdx.x, blk = blockIdx.x;
    if (t < NBUCK) cur[t] = offs[t * NBLK + blk];
    __syncthreads();
    int s = blk * EPB, e = min(E, s + EPB);
    for (int i = s + t; i < e; i += 256) {
        int src = ei[i], dst = ei[E + i];
        int p = atomicAdd(&cur[dst >> BSH], 1);
        ebuf[p] = (src << BSH) | (dst & 255);
    }
}

// 4: merged per-bucket degree-count + scan + CSR fill (edges LDS-cached).
// csr rows: [self][edges...]; entries are src indices only.
__global__ __launch_bounds__(256) void browfill_kernel(const int* __restrict__ ebuf,
                                                       const int* __restrict__ offs,
                                                       int* __restrict__ rowptr,
                                                       float* __restrict__ dinv,
                                                       int* __restrict__ csr,
                                                       int N, int E, int NBLK, int NBUCK) {
    __shared__ int eld[LDSCAP];
    __shared__ int dcnt[256];
    __shared__ int sc[256];
    __shared__ int cur[256];
    int t = threadIdx.x, B = blockIdx.x;
    int beg = offs[B * NBLK];
    int end = (B + 1 < NBUCK) ? offs[(B + 1) * NBLK] : E;
    int cnt = end - beg;
    bool inlds = (cnt <= LDSCAP);

    dcnt[t] = 0;
    __syncthreads();
    if (inlds) {
        for (int i = t; i < cnt; i += 256) {
            int p = ebuf[beg + i];
            eld[i] = p;
            atomicAdd(&dcnt[p & 255], 1);
        }
    } else {
        for (int i = t; i < cnt; i += 256)
            atomicAdd(&dcnt[ebuf[beg + i] & 255], 1);
    }
    __syncthreads();

    int v = B * 256 + t;
    int d = (v < N) ? dcnt[t] + 1 : 0;     // +1: self-loop slot
    sc[t] = d;
    __syncthreads();
    for (int off = 1; off < 256; off <<= 1) {
        int vv = (t >= off) ? sc[t - off] : 0;
        __syncthreads();
        sc[t] += vv;
        __syncthreads();
    }
    int base = beg + B * 256;              // bucket csr start (prior buckets' self slots)
    if (v < N) {
        int rp = base + sc[t] - d;
        rowptr[v] = rp;
        dinv[v] = rsqrtf((float)(dcnt[t] + 1));
        csr[rp] = v;                       // self-loop entry
        cur[t] = rp + 1;
    } else {
        cur[t] = 0;
    }
    if (B == 0 && t == 0) rowptr[N] = E + N;
    __syncthreads();

    if (inlds) {
        for (int i = t; i < cnt; i += 256) {
            int p = eld[i];
            int pos = atomicAdd(&cur[p & 255], 1);
            csr[pos] = p >> BSH;
        }
    } else {
        for (int i = t; i < cnt; i += 256) {
            int p = ebuf[beg + i];
            int pos = atomicAdd(&cur[p & 255], 1);
            csr[pos] = p >> BSH;
        }
    }
}

// ---------- dense GEMM: h[N,64] = dinv[r] * (x[N,K] @ W[K,64]) (LDS-staged) ----------
template <int K>
__global__ __launch_bounds__(256) void gemm_kernel(const float* __restrict__ x,
                                                   const float* __restrict__ W,
                                                   const float* __restrict__ dinv,
                                                   float* __restrict__ h, int N) {
    __shared__ float4 sX4[64][K / 4];
    __shared__ float  sW[K][64];
    int t = threadIdx.x;
    int r0 = blockIdx.x * 64;

    const float4* W4 = (const float4*)W;
    for (int v = t; v < K * 16; v += 256) {
        int k = v >> 4, c4 = v & 15;
        *(float4*)&sW[k][c4 * 4] = W4[v];
    }
    for (int v = t; v < 64 * (K / 4); v += 256) {
        int row = v / (K / 4), c4 = v % (K / 4);
        int gr = min(r0 + row, N - 1);
        sX4[row][c4] = *(const float4*)(x + (size_t)gr * K + 4 * c4);
    }
    __syncthreads();

    int c = t & 63;
    int w = t >> 6;
    float acc[16];
#pragma unroll
    for (int r = 0; r < 16; ++r) acc[r] = 0.f;

#pragma unroll 2
    for (int k4 = 0; k4 < K / 4; ++k4) {
        float w0 = sW[4 * k4 + 0][c];
        float w1 = sW[4 * k4 + 1][c];
        float w2 = sW[4 * k4 + 2][c];
        float w3 = sW[4 * k4 + 3][c];
#pragma unroll
        for (int r = 0; r < 16; ++r) {
            float4 xv = sX4[w * 16 + r][k4];    // broadcast
            acc[r] = fmaf(xv.x, w0, acc[r]);
            acc[r] = fmaf(xv.y, w1, acc[r]);
            acc[r] = fmaf(xv.z, w2, acc[r]);
            acc[r] = fmaf(xv.w, w3, acc[r]);
        }
    }

#pragma unroll
    for (int r = 0; r < 16; ++r) {
        int row = r0 + w * 16 + r;
        if (row < N) h[(size_t)row * DH + c] = acc[r] * dinv[row];
    }
}

// ---------- sparse aggregation: wave per node, 4 edges per VMEM instr ----------
// csr entries are src indices of pre-scaled rows; out = dinv[dst]*Sum + bias, relu.
__global__ __launch_bounds__(256) void agg_kernel(const float* __restrict__ h,
                                                  const int* __restrict__ csr,
                                                  const int* __restrict__ rowptr,
                                                  const float* __restrict__ dinv,
                                                  const float* __restrict__ bias,
                                                  float* __restrict__ out, int N) {
    int lane = threadIdx.x & 63;
    int node = blockIdx.x * (blockDim.x >> 6) + (threadIdx.x >> 6);
    if (node >= N) return;
    int g = lane >> 4;        // edge group 0..3
    int s = lane & 15;        // float4 index within row

    float4 acc0 = {0.f, 0.f, 0.f, 0.f};
    float4 acc1 = {0.f, 0.f, 0.f, 0.f};
    float4 acc2 = {0.f, 0.f, 0.f, 0.f};
    float4 acc3 = {0.f, 0.f, 0.f, 0.f};
    int beg = rowptr[node], end = rowptr[node + 1];
    int i = beg;
    for (; i + 16 <= end; i += 16) {
        int sa = csr[i + g];
        int sb = csr[i + 4 + g];
        int sc_ = csr[i + 8 + g];
        int sd = csr[i + 12 + g];
        float4 ha = ((const float4*)(h + (size_t)sa * DH))[s];
        float4 hb = ((const float4*)(h + (size_t)sb * DH))[s];
        float4 hc = ((const float4*)(h + (size_t)sc_ * DH))[s];
        float4 hd = ((const float4*)(h + (size_t)sd * DH))[s];
        acc0.x += ha.x; acc0.y += ha.y; acc0.z += ha.z; acc0.w += ha.w;
        acc1.x += hb.x; acc1.y += hb.y; acc1.z += hb.z; acc1.w += hb.w;
        acc2.x += hc.x; acc2.y += hc.y; acc2.z += hc.z; acc2.w += hc.w;
        acc3.x += hd.x; acc3.y += hd.y; acc3.z += hd.z; acc3.w += hd.w;
    }
    for (; i + 8 <= end; i += 8) {
        int sa = csr[i + g];
        int sb = csr[i + 4 + g];
        float4 ha = ((const float4*)(h + (size_t)sa * DH))[s];
        float4 hb = ((const float4*)(h + (size_t)sb * DH))[s];
        acc0.x += ha.x; acc0.y += ha.y; acc0.z += ha.z; acc0.w += ha.w;
        acc1.x += hb.x; acc1.y += hb.y; acc1.z += hb.z; acc1.w += hb.w;
    }
    if (i + 4 <= end) {
        int sa = csr[i + g];
        float4 ha = ((const float4*)(h + (size_t)sa * DH))[s];
        acc0.x += ha.x; acc0.y += ha.y; acc0.z += ha.z; acc0.w += ha.w;
        i += 4;
    }
    if (i + g < end) {        // remainder 0..3 edges, one per group
        int sa = csr[i + g];
        float4 ha = ((const float4*)(h + (size_t)sa * DH))[s];
        acc2.x += ha.x; acc2.y += ha.y; acc2.z += ha.z; acc2.w += ha.w;
    }
    float4 acc;
    acc.x = (acc0.x + acc1.x) + (acc2.x + acc3.x);
    acc.y = (acc0.y + acc1.y) + (acc2.y + acc3.y);
    acc.z = (acc0.z + acc1.z) + (acc2.z + acc3.z);
    acc.w = (acc0.w + acc1.w) + (acc2.w + acc3.w);

    // butterfly-reduce across the 4 groups (lanes differing in bits 4,5)
    acc.x += __shfl_xor(acc.x, 16); acc.y += __shfl_xor(acc.y, 16);
    acc.z += __shfl_xor(acc.z, 16); acc.w += __shfl_xor(acc.w, 16);
    acc.x += __shfl_xor(acc.x, 32); acc.y += __shfl_xor(acc.y, 32);
    acc.z += __shfl_xor(acc.z, 32); acc.w += __shfl_xor(acc.w, 32);

    if (g == 0) {
        float dv = dinv[node];
        float4 bv = ((const float4*)bias)[s];
        float4 o;
        o.x = fmaxf(fmaf(dv, acc.x, bv.x), 0.f);
        o.y = fmaxf(fmaf(dv, acc.y, bv.y), 0.f);
        o.z = fmaxf(fmaf(dv, acc.z, bv.z), 0.f);
        o.w = fmaxf(fmaf(dv, acc.w, bv.w), 0.f);
        ((float4*)(out + (size_t)node * DH))[s] = o;
    }
}

// ---------- mean pool over sorted batch (JK-cat of x1,x2) ----------
__global__ __launch_bounds__(128) void pool_kernel(const float* __restrict__ x1,
                                                   const float* __restrict__ x2,
                                                   const int* __restrict__ batch,
                                                   float* __restrict__ pool,
                                                   float* __restrict__ cntf,
                                                   int N, int nodesPerBlock) {
    int f = threadIdx.x;  // 0..127
    int start = blockIdx.x * nodesPerBlock;
    int end = min(N, start + nodesPerBlock);
    if (start >= end) return;
    int gcur = batch[start];
    float acc = 0.f;
    int c = 0;
    for (int v = start; v < end; ++v) {
        int g = batch[v];               // uniform across block
        if (g != gcur) {
            atomicAdd(&pool[gcur * 128 + f], acc);
            if (f == 0) atomicAdd(&cntf[gcur], (float)c);
            acc = 0.f; c = 0; gcur = g;
        }
        acc += (f < DH) ? x1[(size_t)v * DH + f] : x2[(size_t)v * DH + (f - DH)];
        ++c;
    }
    atomicAdd(&pool[gcur * 128 + f], acc);
    if (f == 0) atomicAdd(&cntf[gcur], (float)c);
}

// ---------- head: (pool/cnt) @ Wlin + blin ----------
__global__ __launch_bounds__(512) void final_kernel(const float* __restrict__ pool,
                                                    const float* __restrict__ cntf,
                                                    const float* __restrict__ Wlin,
                                                    const float* __restrict__ blin,
                                                    float* __restrict__ out) {
    int t = threadIdx.x;
    if (t >= NUM_GRAPHS * DOUT) return;
    int g = t / DOUT, o = t % DOUT;
    float inv = 1.0f / fmaxf(cntf[g], 1.0f);
    float acc = 0.f;
    for (int k = 0; k < 2 * DH; ++k)
        acc = fmaf(pool[g * 128 + k], Wlin[k * DOUT + o], acc);
    out[t] = acc * inv + blin[o];
}

extern "C" void kernel_launch(void* const* d_in, const int* in_sizes, int n_in,
                              void* d_out, int out_size, void* d_ws, size_t ws_size,
                              hipStream_t stream) {
    const float* x    = (const float*)d_in[0];
    const int*   ei   = (const int*)d_in[1];
    const int*   batch= (const int*)d_in[2];
    const float* W1   = (const float*)d_in[3];
    const float* b1   = (const float*)d_in[4];
    const float* W2   = (const float*)d_in[5];
    const float* b2   = (const float*)d_in[6];
    const float* Wlin = (const float*)d_in[7];
    const float* blin = (const float*)d_in[8];
    float* out = (float*)d_out;

    const int N = in_sizes[2];            // 50000
    const int E = in_sizes[1] / 2;        // 800000
    const int DIN = in_sizes[0] / N;      // 128
    const int NBUCK = (N + 255) >> BSH;   // 196 buckets of 256 nodes
    const int NBLK = (E + EPB - 1) / EPB; // 98 scatter blocks
    const int L = NBUCK * NBLK;           // hist length (~19.2K)
    const int LB = (L + 255) / 256;       // scan blocks for hist

    // workspace carve-up (256B aligned)
    char* base = (char*)d_ws;
    size_t off = 0;
    auto alloc = [&](size_t bytes) {
        char* p = base + off;
        off = (off + bytes + 255) & ~(size_t)255;
        return p;
    };
    int*   hist   = (int*)  alloc((size_t)L * 4);
    int*   offs   = (int*)  alloc((size_t)L * 4);
    int*   bsum   = (int*)  alloc((size_t)LB * 4);
    int*   rowptr = (int*)  alloc((size_t)(N + 1) * 4);
    float* dinv   = (float*)alloc((size_t)N * 4);
    int*   ebuf   = (int*)  alloc((size_t)E * 4);          // packed (src<<8)|(dst&255)
    int*   csr    = (int*)  alloc((size_t)(E + N) * 4);    // src indices, incl. self
    float* h      = (float*)alloc((size_t)N * DH * 4);     // reused for layer-2 pre-agg
    float* x1     = (float*)alloc((size_t)N * DH * 4);
    float* x2     = (float*)alloc((size_t)N * DH * 4);
    float* pool   = (float*)alloc((size_t)NUM_GRAPHS * 128 * 4);
    float* cntf   = (float*)alloc((size_t)NUM_GRAPHS * 4);
    (void)ws_size; (void)n_in; (void)out_size; (void)DIN;

    // pool and cntf are adjacent: one memset covers both
    hipMemsetAsync(pool, 0, (size_t)NUM_GRAPHS * 128 * 4 + (size_t)NUM_GRAPHS * 4, stream);

    // CSR build: radix partition (block-private write ranges -> line-local writes)
    hist_kernel<<<NBLK, 256, 0, stream>>>(ei, hist, E, NBLK, NBUCK);
    partial_kernel<<<LB, 256, 0, stream>>>(hist, bsum, L);
    escan_kernel<<<LB, 256, 0, stream>>>(hist, bsum, offs, L);
    scatter_kernel<<<NBLK, 256, 0, stream>>>(ei, offs, ebuf, E, NBLK, NBUCK);
    browfill_kernel<<<NBUCK, 256, 0, stream>>>(ebuf, offs, rowptr, dinv, csr, N, E, NBLK, NBUCK);

    // layer 1: 64 rows per block; gemm pre-scales rows by dinv
    gemm_kernel<128><<<(N + 63) / 64, 256, 0, stream>>>(x, W1, dinv, h, N);
    agg_kernel<<<(N + 3) / 4, 256, 0, stream>>>(h, csr, rowptr, dinv, b1, x1, N);
    // layer 2 (h buffer reused)
    gemm_kernel<64><<<(N + 63) / 64, 256, 0, stream>>>(x1, W2, dinv, h, N);
    agg_kernel<<<(N + 3) / 4, 256, 0, stream>>>(h, csr, rowptr, dinv, b2, x2, N);

    // pooling + head
    const int nodesPerBlock = 32;
    pool_kernel<<<(N + nodesPerBlock - 1) / nodesPerBlock, 128, 0, stream>>>(
        x1, x2, batch, pool, cntf, N, nodesPerBlock);
    final_kernel<<<1, 512, 0, stream>>>(pool, cntf, Wlin, blin, out);
}

// Round 12
// 255.087 us; speedup vs baseline: 1.5869x; 1.0646x over previous
//
#include <hip/hip_runtime.h>

static constexpr int NUM_GRAPHS = 64;
static constexpr int DH = 64;      // hidden dim == wave size
static constexpr int DOUT = 7;
static constexpr int EPB = 8192;   // edges per scatter block
static constexpr int BSH = 8;      // bucket shift: 256 nodes per bucket
static constexpr int LDSCAP = 8192; // max edges cached in LDS per bucket

__device__ __forceinline__ unsigned short f2bf(float f) {   // RNE f32 -> bf16
    unsigned u = __float_as_uint(f);
    u = (u + 0x7FFF + ((u >> 16) & 1)) >> 16;
    return (unsigned short)u;
}
__device__ __forceinline__ float bf2f(unsigned short b) {
    return __uint_as_float((unsigned)b << 16);
}

// ---------- CSR build: radix partition by dst-bucket, block-private ranges ----------
// Edge payload packed: (src << 8) | (dst & 255). Weights factored out:
// gemm pre-scales rows by dinv[src] (and packs bf16), agg post-scales by dinv[dst].

// 1: per-block histogram over buckets -> hist[bucket][blk] (bucket-major)
__global__ __launch_bounds__(256) void hist_kernel(const int* __restrict__ ei,
                                                   int* __restrict__ hist,
                                                   int E, int NBLK, int NBUCK) {
    __shared__ int lh[256];
    int t = threadIdx.x, blk = blockIdx.x;
    lh[t] = 0;
    __syncthreads();
    int s = blk * EPB, e = min(E, s + EPB);
    for (int i = s + t; i < e; i += 256)
        atomicAdd(&lh[ei[E + i] >> BSH], 1);
    __syncthreads();
    if (t < NBUCK) hist[t * NBLK + blk] = lh[t];
}

// 2a: per-block sums of an int array (generic)
__global__ __launch_bounds__(256) void partial_kernel(const int* __restrict__ in,
                                                      int* __restrict__ bsum, int L) {
    __shared__ int sh[256];
    int t = threadIdx.x;
    int i = blockIdx.x * 256 + t;
    sh[t] = (i < L) ? in[i] : 0;
    __syncthreads();
    for (int s = 128; s > 0; s >>= 1) {
        if (t < s) sh[t] += sh[t + s];
        __syncthreads();
    }
    if (t == 0) bsum[blockIdx.x] = sh[0];
}

// 2b: exclusive scan using per-block sums (generic)
__global__ __launch_bounds__(256) void escan_kernel(const int* __restrict__ in,
                                                    const int* __restrict__ bsum,
                                                    int* __restrict__ offs, int L) {
    __shared__ int red[256];
    __shared__ int sh[256];
    int t = threadIdx.x, b = blockIdx.x, i = b * 256 + t;
    int part = 0;
    for (int j = t; j < b; j += 256) part += bsum[j];
    red[t] = part;
    __syncthreads();
    for (int s = 128; s > 0; s >>= 1) {
        if (t < s) red[t] += red[t + s];
        __syncthreads();
    }
    int base = red[0];
    int d = (i < L) ? in[i] : 0;
    sh[t] = d;
    __syncthreads();
    for (int off = 1; off < 256; off <<= 1) {
        int v = (t >= off) ? sh[t - off] : 0;
        __syncthreads();
        sh[t] += v;
        __syncthreads();
    }
    if (i < L) offs[i] = base + sh[t] - d;
}

// 3: scatter packed edges into bucket-grouped ebuf (block-private sub-ranges)
__global__ __launch_bounds__(256) void scatter_kernel(const int* __restrict__ ei,
                                                      const int* __restrict__ offs,
                                                      int* __restrict__ ebuf,
                                                      int E, int NBLK, int NBUCK) {
    __shared__ int cur[256];
    int t = threadIdx.x, blk = blockIdx.x;
    if (t < NBUCK) cur[t] = offs[t * NBLK + blk];
    __syncthreads();
    int s = blk * EPB, e = min(E, s + EPB);
    for (int i = s + t; i < e; i += 256) {
        int src = ei[i], dst = ei[E + i];
        int p = atomicAdd(&cur[dst >> BSH], 1);
        ebuf[p] = (src << BSH) | (dst & 255);
    }
}

// 4: merged per-bucket degree-count + scan + CSR fill (edges LDS-cached).
__global__ __launch_bounds__(256) void browfill_kernel(const int* __restrict__ ebuf,
                                                       const int* __restrict__ offs,
                                                       int* __restrict__ rowptr,
                                                       float* __restrict__ dinv,
                                                       int* __restrict__ csr,
                                                       int N, int E, int NBLK, int NBUCK) {
    __shared__ int eld[LDSCAP];
    __shared__ int dcnt[256];
    __shared__ int sc[256];
    __shared__ int cur[256];
    int t = threadIdx.x, B = blockIdx.x;
    int beg = offs[B * NBLK];
    int end = (B + 1 < NBUCK) ? offs[(B + 1) * NBLK] : E;
    int cnt = end - beg;
    bool inlds = (cnt <= LDSCAP);

    dcnt[t] = 0;
    __syncthreads();
    if (inlds) {
        for (int i = t; i < cnt; i += 256) {
            int p = ebuf[beg + i];
            eld[i] = p;
            atomicAdd(&dcnt[p & 255], 1);
        }
    } else {
        for (int i = t; i < cnt; i += 256)
            atomicAdd(&dcnt[ebuf[beg + i] & 255], 1);
    }
    __syncthreads();

    int v = B * 256 + t;
    int d = (v < N) ? dcnt[t] + 1 : 0;     // +1: self-loop slot
    sc[t] = d;
    __syncthreads();
    for (int off = 1; off < 256; off <<= 1) {
        int vv = (t >= off) ? sc[t - off] : 0;
        __syncthreads();
        sc[t] += vv;
        __syncthreads();
    }
    int base = beg + B * 256;              // bucket csr start (prior buckets' self slots)
    if (v < N) {
        int rp = base + sc[t] - d;
        rowptr[v] = rp;
        dinv[v] = rsqrtf((float)(dcnt[t] + 1));
        csr[rp] = v;                       // self-loop entry
        cur[t] = rp + 1;
    } else {
        cur[t] = 0;
    }
    if (B == 0 && t == 0) rowptr[N] = E + N;
    __syncthreads();

    if (inlds) {
        for (int i = t; i < cnt; i += 256) {
            int p = eld[i];
            int pos = atomicAdd(&cur[p & 255], 1);
            csr[pos] = p >> BSH;
        }
    } else {
        for (int i = t; i < cnt; i += 256) {
            int p = ebuf[beg + i];
            int pos = atomicAdd(&cur[p & 255], 1);
            csr[pos] = p >> BSH;
        }
    }
}

// ---------- dense GEMM: hb[N,64] = bf16(dinv[r] * (x[N,K] @ W[K,64])) ----------
template <int K>
__global__ __launch_bounds__(256) void gemm_kernel(const float* __restrict__ x,
                                                   const float* __restrict__ W,
                                                   const float* __restrict__ dinv,
                                                   unsigned short* __restrict__ hb, int N) {
    __shared__ float4 sX4[64][K / 4];
    __shared__ float  sW[K][64];
    int t = threadIdx.x;
    int r0 = blockIdx.x * 64;

    const float4* W4 = (const float4*)W;
    for (int v = t; v < K * 16; v += 256) {
        int k = v >> 4, c4 = v & 15;
        *(float4*)&sW[k][c4 * 4] = W4[v];
    }
    for (int v = t; v < 64 * (K / 4); v += 256) {
        int row = v / (K / 4), c4 = v % (K / 4);
        int gr = min(r0 + row, N - 1);
        sX4[row][c4] = *(const float4*)(x + (size_t)gr * K + 4 * c4);
    }
    __syncthreads();

    int c = t & 63;
    int w = t >> 6;
    float acc[16];
#pragma unroll
    for (int r = 0; r < 16; ++r) acc[r] = 0.f;

#pragma unroll 2
    for (int k4 = 0; k4 < K / 4; ++k4) {
        float w0 = sW[4 * k4 + 0][c];
        float w1 = sW[4 * k4 + 1][c];
        float w2 = sW[4 * k4 + 2][c];
        float w3 = sW[4 * k4 + 3][c];
#pragma unroll
        for (int r = 0; r < 16; ++r) {
            float4 xv = sX4[w * 16 + r][k4];    // broadcast
            acc[r] = fmaf(xv.x, w0, acc[r]);
            acc[r] = fmaf(xv.y, w1, acc[r]);
            acc[r] = fmaf(xv.z, w2, acc[r]);
            acc[r] = fmaf(xv.w, w3, acc[r]);
        }
    }

#pragma unroll
    for (int r = 0; r < 16; ++r) {
        int row = r0 + w * 16 + r;
        if (row < N) hb[(size_t)row * DH + c] = f2bf(acc[r] * dinv[row]);
    }
}

// ---------- sparse aggregation: wave per node, bf16 gathers (half traffic) ----------
// csr entries are src indices of pre-scaled bf16 rows; out = dinv[dst]*Sum + b, relu.
__global__ __launch_bounds__(256) void agg_kernel(const unsigned short* __restrict__ hb,
                                                  const int* __restrict__ csr,
                                                  const int* __restrict__ rowptr,
                                                  const float* __restrict__ dinv,
                                                  const float* __restrict__ bias,
                                                  float* __restrict__ out, int N) {
    int lane = threadIdx.x & 63;
    int node = blockIdx.x * (blockDim.x >> 6) + (threadIdx.x >> 6);
    if (node >= N) return;
    int g = lane >> 4;        // edge group 0..3
    int s = lane & 15;        // ushort4 index within row (4 channels/lane)

    float4 acc0 = {0.f, 0.f, 0.f, 0.f};
    float4 acc1 = {0.f, 0.f, 0.f, 0.f};
    float4 acc2 = {0.f, 0.f, 0.f, 0.f};
    float4 acc3 = {0.f, 0.f, 0.f, 0.f};
    int beg = rowptr[node], end = rowptr[node + 1];
    int i = beg;
    for (; i + 16 <= end; i += 16) {
        int sa = csr[i + g];
        int sb = csr[i + 4 + g];
        int sc_ = csr[i + 8 + g];
        int sd = csr[i + 12 + g];
        ushort4 ua = ((const ushort4*)(hb + (size_t)sa * DH))[s];
        ushort4 ub = ((const ushort4*)(hb + (size_t)sb * DH))[s];
        ushort4 uc = ((const ushort4*)(hb + (size_t)sc_ * DH))[s];
        ushort4 ud = ((const ushort4*)(hb + (size_t)sd * DH))[s];
        acc0.x += bf2f(ua.x); acc0.y += bf2f(ua.y); acc0.z += bf2f(ua.z); acc0.w += bf2f(ua.w);
        acc1.x += bf2f(ub.x); acc1.y += bf2f(ub.y); acc1.z += bf2f(ub.z); acc1.w += bf2f(ub.w);
        acc2.x += bf2f(uc.x); acc2.y += bf2f(uc.y); acc2.z += bf2f(uc.z); acc2.w += bf2f(uc.w);
        acc3.x += bf2f(ud.x); acc3.y += bf2f(ud.y); acc3.z += bf2f(ud.z); acc3.w += bf2f(ud.w);
    }
    for (; i + 8 <= end; i += 8) {
        int sa = csr[i + g];
        int sb = csr[i + 4 + g];
        ushort4 ua = ((const ushort4*)(hb + (size_t)sa * DH))[s];
        ushort4 ub = ((const ushort4*)(hb + (size_t)sb * DH))[s];
        acc0.x += bf2f(ua.x); acc0.y += bf2f(ua.y); acc0.z += bf2f(ua.z); acc0.w += bf2f(ua.w);
        acc1.x += bf2f(ub.x); acc1.y += bf2f(ub.y); acc1.z += bf2f(ub.z); acc1.w += bf2f(ub.w);
    }
    if (i + 4 <= end) {
        int sa = csr[i + g];
        ushort4 ua = ((const ushort4*)(hb + (size_t)sa * DH))[s];
        acc0.x += bf2f(ua.x); acc0.y += bf2f(ua.y); acc0.z += bf2f(ua.z); acc0.w += bf2f(ua.w);
        i += 4;
    }
    if (i + g < end) {        // remainder 0..3 edges, one per group
        int sa = csr[i + g];
        ushort4 ua = ((const ushort4*)(hb + (size_t)sa * DH))[s];
        acc2.x += bf2f(ua.x); acc2.y += bf2f(ua.y); acc2.z += bf2f(ua.z); acc2.w += bf2f(ua.w);
    }
    float4 acc;
    acc.x = (acc0.x + acc1.x) + (acc2.x + acc3.x);
    acc.y = (acc0.y + acc1.y) + (acc2.y + acc3.y);
    acc.z = (acc0.z + acc1.z) + (acc2.z + acc3.z);
    acc.w = (acc0.w + acc1.w) + (acc2.w + acc3.w);

    // butterfly-reduce across the 4 groups (lanes differing in bits 4,5)
    acc.x += __shfl_xor(acc.x, 16); acc.y += __shfl_xor(acc.y, 16);
    acc.z += __shfl_xor(acc.z, 16); acc.w += __shfl_xor(acc.w, 16);
    acc.x += __shfl_xor(acc.x, 32); acc.y += __shfl_xor(acc.y, 32);
    acc.z += __shfl_xor(acc.z, 32); acc.w += __shfl_xor(acc.w, 32);

    if (g == 0) {
        float dv = dinv[node];
        float4 bv = ((const float4*)bias)[s];
        float4 o;
        o.x = fmaxf(fmaf(dv, acc.x, bv.x), 0.f);
        o.y = fmaxf(fmaf(dv, acc.y, bv.y), 0.f);
        o.z = fmaxf(fmaf(dv, acc.z, bv.z), 0.f);
        o.w = fmaxf(fmaf(dv, acc.w, bv.w), 0.f);
        ((float4*)(out + (size_t)node * DH))[s] = o;
    }
}

// ---------- mean pool over sorted batch (JK-cat of x1,x2) ----------
__global__ __launch_bounds__(128) void pool_kernel(const float* __restrict__ x1,
                                                   const float* __restrict__ x2,
                                                   const int* __restrict__ batch,
                                                   float* __restrict__ pool,
                                                   float* __restrict__ cntf,
                                                   int N, int nodesPerBlock) {
    int f = threadIdx.x;  // 0..127
    int start = blockIdx.x * nodesPerBlock;
    int end = min(N, start + nodesPerBlock);
    if (start >= end) return;
    int gcur = batch[start];
    float acc = 0.f;
    int c = 0;
    for (int v = start; v < end; ++v) {
        int g = batch[v];               // uniform across block
        if (g != gcur) {
            atomicAdd(&pool[gcur * 128 + f], acc);
            if (f == 0) atomicAdd(&cntf[gcur], (float)c);
            acc = 0.f; c = 0; gcur = g;
        }
        acc += (f < DH) ? x1[(size_t)v * DH + f] : x2[(size_t)v * DH + (f - DH)];
        ++c;
    }
    atomicAdd(&pool[gcur * 128 + f], acc);
    if (f == 0) atomicAdd(&cntf[gcur], (float)c);
}

// ---------- head: (pool/cnt) @ Wlin + blin ----------
__global__ __launch_bounds__(512) void final_kernel(const float* __restrict__ pool,
                                                    const float* __restrict__ cntf,
                                                    const float* __restrict__ Wlin,
                                                    const float* __restrict__ blin,
                                                    float* __restrict__ out) {
    int t = threadIdx.x;
    if (t >= NUM_GRAPHS * DOUT) return;
    int g = t / DOUT, o = t % DOUT;
    float inv = 1.0f / fmaxf(cntf[g], 1.0f);
    float acc = 0.f;
    for (int k = 0; k < 2 * DH; ++k)
        acc = fmaf(pool[g * 128 + k], Wlin[k * DOUT + o], acc);
    out[t] = acc * inv + blin[o];
}

extern "C" void kernel_launch(void* const* d_in, const int* in_sizes, int n_in,
                              void* d_out, int out_size, void* d_ws, size_t ws_size,
                              hipStream_t stream) {
    const float* x    = (const float*)d_in[0];
    const int*   ei   = (const int*)d_in[1];
    const int*   batch= (const int*)d_in[2];
    const float* W1   = (const float*)d_in[3];
    const float* b1   = (const float*)d_in[4];
    const float* W2   = (const float*)d_in[5];
    const float* b2   = (const float*)d_in[6];
    const float* Wlin = (const float*)d_in[7];
    const float* blin = (const float*)d_in[8];
    float* out = (float*)d_out;

    const int N = in_sizes[2];            // 50000
    const int E = in_sizes[1] / 2;        // 800000
    const int DIN = in_sizes[0] / N;      // 128
    const int NBUCK = (N + 255) >> BSH;   // 196 buckets of 256 nodes
    const int NBLK = (E + EPB - 1) / EPB; // 98 scatter blocks
    const int L = NBUCK * NBLK;           // hist length (~19.2K)
    const int LB = (L + 255) / 256;       // scan blocks for hist

    // workspace carve-up (256B aligned)
    char* base = (char*)d_ws;
    size_t off = 0;
    auto alloc = [&](size_t bytes) {
        char* p = base + off;
        off = (off + bytes + 255) & ~(size_t)255;
        return p;
    };
    int*   hist   = (int*)  alloc((size_t)L * 4);
    int*   offs   = (int*)  alloc((size_t)L * 4);
    int*   bsum   = (int*)  alloc((size_t)LB * 4);
    int*   rowptr = (int*)  alloc((size_t)(N + 1) * 4);
    float* dinv   = (float*)alloc((size_t)N * 4);
    int*   ebuf   = (int*)  alloc((size_t)E * 4);          // packed (src<<8)|(dst&255)
    int*   csr    = (int*)  alloc((size_t)(E + N) * 4);    // src indices, incl. self
    unsigned short* hb = (unsigned short*)alloc((size_t)N * DH * 2);  // bf16 pre-scaled rows
    float* x1     = (float*)alloc((size_t)N * DH * 4);
    float* x2     = (float*)alloc((size_t)N * DH * 4);
    float* pool   = (float*)alloc((size_t)NUM_GRAPHS * 128 * 4);
    float* cntf   = (float*)alloc((size_t)NUM_GRAPHS * 4);
    (void)ws_size; (void)n_in; (void)out_size; (void)DIN;

    // pool and cntf are adjacent: one memset covers both
    hipMemsetAsync(pool, 0, (size_t)NUM_GRAPHS * 128 * 4 + (size_t)NUM_GRAPHS * 4, stream);

    // CSR build: radix partition (block-private write ranges -> line-local writes)
    hist_kernel<<<NBLK, 256, 0, stream>>>(ei, hist, E, NBLK, NBUCK);
    partial_kernel<<<LB, 256, 0, stream>>>(hist, bsum, L);
    escan_kernel<<<LB, 256, 0, stream>>>(hist, bsum, offs, L);
    scatter_kernel<<<NBLK, 256, 0, stream>>>(ei, offs, ebuf, E, NBLK, NBUCK);
    browfill_kernel<<<NBUCK, 256, 0, stream>>>(ebuf, offs, rowptr, dinv, csr, N, E, NBLK, NBUCK);

    // layer 1: gemm pre-scales rows by dinv and packs bf16
    gemm_kernel<128><<<(N + 63) / 64, 256, 0, stream>>>(x, W1, dinv, hb, N);
    agg_kernel<<<(N + 3) / 4, 256, 0, stream>>>(hb, csr, rowptr, dinv, b1, x1, N);
    // layer 2 (hb buffer reused)
    gemm_kernel<64><<<(N + 63) / 64, 256, 0, stream>>>(x1, W2, dinv, hb, N);
    agg_kernel<<<(N + 3) / 4, 256, 0, stream>>>(hb, csr, rowptr, dinv, b2, x2, N);

    // pooling + head
    const int nodesPerBlock = 32;
    pool_kernel<<<(N + nodesPerBlock - 1) / nodesPerBlock, 128, 0, stream>>>(
        x1, x2, batch, pool, cntf, N, nodesPerBlock);
    final_kernel<<<1, 512, 0, stream>>>(pool, cntf, Wlin, blin, out);
}

// Round 14
// 236.420 us; speedup vs baseline: 1.7122x; 1.0790x over previous
//
#include <hip/hip_runtime.h>

static constexpr int NUM_GRAPHS = 64;
static constexpr int DH = 64;      // hidden dim == wave size
static constexpr int DOUT = 7;
static constexpr int EPB = 8192;   // edges per scatter block
static constexpr int BSH = 8;      // bucket shift: 256 nodes per bucket
static constexpr int LDSCAP = 8192; // max edges cached in LDS per bucket

__device__ __forceinline__ unsigned short f2bf(float f) {   // RNE f32 -> bf16
    unsigned u = __float_as_uint(f);
    u = (u + 0x7FFF + ((u >> 16) & 1)) >> 16;
    return (unsigned short)u;
}
__device__ __forceinline__ float bf2f(unsigned short b) {
    return __uint_as_float((unsigned)b << 16);
}

// ---------- CSR build: radix partition by dst-bucket, block-private ranges ----------
// Edge payload packed: (src << 8) | (dst & 255). Weights factored out:
// gemm pre-scales rows by dinv[src] (and packs bf16), agg post-scales by dinv[dst].

// 1: per-block histogram over buckets -> hist[bucket][blk] (bucket-major)
__global__ __launch_bounds__(256) void hist_kernel(const int* __restrict__ ei,
                                                   int* __restrict__ hist,
                                                   int E, int NBLK, int NBUCK) {
    __shared__ int lh[256];
    int t = threadIdx.x, blk = blockIdx.x;
    lh[t] = 0;
    __syncthreads();
    int s = blk * EPB, e = min(E, s + EPB);
    for (int i = s + t; i < e; i += 256)
        atomicAdd(&lh[ei[E + i] >> BSH], 1);
    __syncthreads();
    if (t < NBUCK) hist[t * NBLK + blk] = lh[t];
}

// 2a: per-block sums of an int array (generic)
__global__ __launch_bounds__(256) void partial_kernel(const int* __restrict__ in,
                                                      int* __restrict__ bsum, int L) {
    __shared__ int sh[256];
    int t = threadIdx.x;
    int i = blockIdx.x * 256 + t;
    sh[t] = (i < L) ? in[i] : 0;
    __syncthreads();
    for (int s = 128; s > 0; s >>= 1) {
        if (t < s) sh[t] += sh[t + s];
        __syncthreads();
    }
    if (t == 0) bsum[blockIdx.x] = sh[0];
}

// 2b: exclusive scan using per-block sums (generic)
__global__ __launch_bounds__(256) void escan_kernel(const int* __restrict__ in,
                                                    const int* __restrict__ bsum,
                                                    int* __restrict__ offs, int L) {
    __shared__ int red[256];
    __shared__ int sh[256];
    int t = threadIdx.x, b = blockIdx.x, i = b * 256 + t;
    int part = 0;
    for (int j = t; j < b; j += 256) part += bsum[j];
    red[t] = part;
    __syncthreads();
    for (int s = 128; s > 0; s >>= 1) {
        if (t < s) red[t] += red[t + s];
        __syncthreads();
    }
    int base = red[0];
    int d = (i < L) ? in[i] : 0;
    sh[t] = d;
    __syncthreads();
    for (int off = 1; off < 256; off <<= 1) {
        int v = (t >= off) ? sh[t - off] : 0;
        __syncthreads();
        sh[t] += v;
        __syncthreads();
    }
    if (i < L) offs[i] = base + sh[t] - d;
}

// 3: scatter packed edges into bucket-grouped ebuf (block-private sub-ranges)
__global__ __launch_bounds__(256) void scatter_kernel(const int* __restrict__ ei,
                                                      const int* __restrict__ offs,
                                                      int* __restrict__ ebuf,
                                                      int E, int NBLK, int NBUCK) {
    __shared__ int cur[256];
    int t = threadIdx.x, blk = blockIdx.x;
    if (t < NBUCK) cur[t] = offs[t * NBLK + blk];
    __syncthreads();
    int s = blk * EPB, e = min(E, s + EPB);
    for (int i = s + t; i < e; i += 256) {
        int src = ei[i], dst = ei[E + i];
        int p = atomicAdd(&cur[dst >> BSH], 1);
        ebuf[p] = (src << BSH) | (dst & 255);
    }
}

// 4: merged per-bucket degree-count + scan + CSR fill (edges LDS-cached).
__global__ __launch_bounds__(256) void browfill_kernel(const int* __restrict__ ebuf,
                                                       const int* __restrict__ offs,
                                                       int* __restrict__ rowptr,
                                                       float* __restrict__ dinv,
                                                       int* __restrict__ csr,
                                                       int N, int E, int NBLK, int NBUCK) {
    __shared__ int eld[LDSCAP];
    __shared__ int dcnt[256];
    __shared__ int sc[256];
    __shared__ int cur[256];
    int t = threadIdx.x, B = blockIdx.x;
    int beg = offs[B * NBLK];
    int end = (B + 1 < NBUCK) ? offs[(B + 1) * NBLK] : E;
    int cnt = end - beg;
    bool inlds = (cnt <= LDSCAP);

    dcnt[t] = 0;
    __syncthreads();
    if (inlds) {
        for (int i = t; i < cnt; i += 256) {
            int p = ebuf[beg + i];
            eld[i] = p;
            atomicAdd(&dcnt[p & 255], 1);
        }
    } else {
        for (int i = t; i < cnt; i += 256)
            atomicAdd(&dcnt[ebuf[beg + i] & 255], 1);
    }
    __syncthreads();

    int v = B * 256 + t;
    int d = (v < N) ? dcnt[t] + 1 : 0;     // +1: self-loop slot
    sc[t] = d;
    __syncthreads();
    for (int off = 1; off < 256; off <<= 1) {
        int vv = (t >= off) ? sc[t - off] : 0;
        __syncthreads();
        sc[t] += vv;
        __syncthreads();
    }
    int base = beg + B * 256;              // bucket csr start (prior buckets' self slots)
    if (v < N) {
        int rp = base + sc[t] - d;
        rowptr[v] = rp;
        dinv[v] = rsqrtf((float)(dcnt[t] + 1));
        csr[rp] = v;                       // self-loop entry
        cur[t] = rp + 1;
    } else {
        cur[t] = 0;
    }
    if (B == 0 && t == 0) rowptr[N] = E + N;
    __syncthreads();

    if (inlds) {
        for (int i = t; i < cnt; i += 256) {
            int p = eld[i];
            int pos = atomicAdd(&cur[p & 255], 1);
            csr[pos] = p >> BSH;
        }
    } else {
        for (int i = t; i < cnt; i += 256) {
            int p = ebuf[beg + i];
            int pos = atomicAdd(&cur[p & 255], 1);
            csr[pos] = p >> BSH;
        }
    }
}

// ---------- dense GEMM: hb[N,64] = bf16(dinv[r] * (x[N,K] @ W[K,64])) ----------
// 4x4 register tile per thread: per k4-iter 8 LDS b128 reads vs 64 FMAs
// (previous layout issued 20 LDS instrs -> LDS-issue bound).
// sX4 rows padded +1 float4: row-group reads land on 2 banks (free) not 1 (4-way).
template <int K>
__global__ __launch_bounds__(256) void gemm_kernel(const float* __restrict__ x,
                                                   const float* __restrict__ W,
                                                   const float* __restrict__ dinv,
                                                   unsigned short* __restrict__ hb, int N) {
    __shared__ float4 sX4[64][K / 4 + 1];
    __shared__ float  sW[K][64];
    int t = threadIdx.x;
    int r0 = blockIdx.x * 64;

    const float4* W4 = (const float4*)W;
    for (int v = t; v < K * 16; v += 256) {
        int k = v >> 4, c4 = v & 15;
        *(float4*)&sW[k][c4 * 4] = W4[v];
    }
    for (int v = t; v < 64 * (K / 4); v += 256) {
        int row = v / (K / 4), c4 = v % (K / 4);
        int gr = min(r0 + row, N - 1);
        sX4[row][c4] = *(const float4*)(x + (size_t)gr * K + 4 * c4);
    }
    __syncthreads();

    int cg = (t & 15) * 4;   // this thread's 4 output columns
    int rg = (t >> 4) * 4;   // this thread's 4 output rows
    float acc[4][4] = {};

#pragma unroll 2
    for (int k4 = 0; k4 < K / 4; ++k4) {
        float xk[4][4];
        float wv[4][4];
#pragma unroll
        for (int i = 0; i < 4; ++i)
            *(float4*)&xk[i][0] = sX4[rg + i][k4];
#pragma unroll
        for (int k = 0; k < 4; ++k)
            *(float4*)&wv[k][0] = *(const float4*)&sW[4 * k4 + k][cg];
#pragma unroll
        for (int i = 0; i < 4; ++i)
#pragma unroll
            for (int j = 0; j < 4; ++j) {
                acc[i][j] = fmaf(xk[i][0], wv[0][j], acc[i][j]);
                acc[i][j] = fmaf(xk[i][1], wv[1][j], acc[i][j]);
                acc[i][j] = fmaf(xk[i][2], wv[2][j], acc[i][j]);
                acc[i][j] = fmaf(xk[i][3], wv[3][j], acc[i][j]);
            }
    }

#pragma unroll
    for (int i = 0; i < 4; ++i) {
        int row = r0 + rg + i;
        if (row < N) {
            float dv = dinv[row];
            ushort4 o;
            o.x = f2bf(acc[i][0] * dv);
            o.y = f2bf(acc[i][1] * dv);
            o.z = f2bf(acc[i][2] * dv);
            o.w = f2bf(acc[i][3] * dv);
            ((ushort4*)(hb + (size_t)row * DH))[t & 15] = o;
        }
    }
}

// ---------- sparse aggregation: wave per node, bf16 gathers (half traffic) ----------
// csr entries are src indices of pre-scaled bf16 rows; out = dinv[dst]*Sum + b, relu.
__global__ __launch_bounds__(256) void agg_kernel(const unsigned short* __restrict__ hb,
                                                  const int* __restrict__ csr,
                                                  const int* __restrict__ rowptr,
                                                  const float* __restrict__ dinv,
                                                  const float* __restrict__ bias,
                                                  float* __restrict__ out, int N) {
    int lane = threadIdx.x & 63;
    int node = blockIdx.x * (blockDim.x >> 6) + (threadIdx.x >> 6);
    if (node >= N) return;
    int g = lane >> 4;        // edge group 0..3
    int s = lane & 15;        // ushort4 index within row (4 channels/lane)

    float4 acc0 = {0.f, 0.f, 0.f, 0.f};
    float4 acc1 = {0.f, 0.f, 0.f, 0.f};
    float4 acc2 = {0.f, 0.f, 0.f, 0.f};
    float4 acc3 = {0.f, 0.f, 0.f, 0.f};
    int beg = rowptr[node], end = rowptr[node + 1];
    int i = beg;
    for (; i + 16 <= end; i += 16) {
        int sa = csr[i + g];
        int sb = csr[i + 4 + g];
        int sc_ = csr[i + 8 + g];
        int sd = csr[i + 12 + g];
        ushort4 ua = ((const ushort4*)(hb + (size_t)sa * DH))[s];
        ushort4 ub = ((const ushort4*)(hb + (size_t)sb * DH))[s];
        ushort4 uc = ((const ushort4*)(hb + (size_t)sc_ * DH))[s];
        ushort4 ud = ((const ushort4*)(hb + (size_t)sd * DH))[s];
        acc0.x += bf2f(ua.x); acc0.y += bf2f(ua.y); acc0.z += bf2f(ua.z); acc0.w += bf2f(ua.w);
        acc1.x += bf2f(ub.x); acc1.y += bf2f(ub.y); acc1.z += bf2f(ub.z); acc1.w += bf2f(ub.w);
        acc2.x += bf2f(uc.x); acc2.y += bf2f(uc.y); acc2.z += bf2f(uc.z); acc2.w += bf2f(uc.w);
        acc3.x += bf2f(ud.x); acc3.y += bf2f(ud.y); acc3.z += bf2f(ud.z); acc3.w += bf2f(ud.w);
    }
    for (; i + 8 <= end; i += 8) {
        int sa = csr[i + g];
        int sb = csr[i + 4 + g];
        ushort4 ua = ((const ushort4*)(hb + (size_t)sa * DH))[s];
        ushort4 ub = ((const ushort4*)(hb + (size_t)sb * DH))[s];
        acc0.x += bf2f(ua.x); acc0.y += bf2f(ua.y); acc0.z += bf2f(ua.z); acc0.w += bf2f(ua.w);
        acc1.x += bf2f(ub.x); acc1.y += bf2f(ub.y); acc1.z += bf2f(ub.z); acc1.w += bf2f(ub.w);
    }
    if (i + 4 <= end) {
        int sa = csr[i + g];
        ushort4 ua = ((const ushort4*)(hb + (size_t)sa * DH))[s];
        acc0.x += bf2f(ua.x); acc0.y += bf2f(ua.y); acc0.z += bf2f(ua.z); acc0.w += bf2f(ua.w);
        i += 4;
    }
    if (i + g < end) {        // remainder 0..3 edges, one per group
        int sa = csr[i + g];
        ushort4 ua = ((const ushort4*)(hb + (size_t)sa * DH))[s];
        acc2.x += bf2f(ua.x); acc2.y += bf2f(ua.y); acc2.z += bf2f(ua.z); acc2.w += bf2f(ua.w);
    }
    float4 acc;
    acc.x = (acc0.x + acc1.x) + (acc2.x + acc3.x);
    acc.y = (acc0.y + acc1.y) + (acc2.y + acc3.y);
    acc.z = (acc0.z + acc1.z) + (acc2.z + acc3.z);
    acc.w = (acc0.w + acc1.w) + (acc2.w + acc3.w);

    // butterfly-reduce across the 4 groups (lanes differing in bits 4,5)
    acc.x += __shfl_xor(acc.x, 16); acc.y += __shfl_xor(acc.y, 16);
    acc.z += __shfl_xor(acc.z, 16); acc.w += __shfl_xor(acc.w, 16);
    acc.x += __shfl_xor(acc.x, 32); acc.y += __shfl_xor(acc.y, 32);
    acc.z += __shfl_xor(acc.z, 32); acc.w += __shfl_xor(acc.w, 32);

    if (g == 0) {
        float dv = dinv[node];
        float4 bv = ((const float4*)bias)[s];
        float4 o;
        o.x = fmaxf(fmaf(dv, acc.x, bv.x), 0.f);
        o.y = fmaxf(fmaf(dv, acc.y, bv.y), 0.f);
        o.z = fmaxf(fmaf(dv, acc.z, bv.z), 0.f);
        o.w = fmaxf(fmaf(dv, acc.w, bv.w), 0.f);
        ((float4*)(out + (size_t)node * DH))[s] = o;
    }
}

// ---------- mean pool over sorted batch (JK-cat of x1,x2) ----------
__global__ __launch_bounds__(128) void pool_kernel(const float* __restrict__ x1,
                                                   const float* __restrict__ x2,
                                                   const int* __restrict__ batch,
                                                   float* __restrict__ pool,
                                                   float* __restrict__ cntf,
                                                   int N, int nodesPerBlock) {
    int f = threadIdx.x;  // 0..127
    int start = blockIdx.x * nodesPerBlock;
    int end = min(N, start + nodesPerBlock);
    if (start >= end) return;
    int gcur = batch[start];
    float acc = 0.f;
    int c = 0;
    for (int v = start; v < end; ++v) {
        int g = batch[v];               // uniform across block
        if (g != gcur) {
            atomicAdd(&pool[gcur * 128 + f], acc);
            if (f == 0) atomicAdd(&cntf[gcur], (float)c);
            acc = 0.f; c = 0; gcur = g;
        }
        acc += (f < DH) ? x1[(size_t)v * DH + f] : x2[(size_t)v * DH + (f - DH)];
        ++c;
    }
    atomicAdd(&pool[gcur * 128 + f], acc);
    if (f == 0) atomicAdd(&cntf[gcur], (float)c);
}

// ---------- head: (pool/cnt) @ Wlin + blin ----------
__global__ __launch_bounds__(512) void final_kernel(const float* __restrict__ pool,
                                                    const float* __restrict__ cntf,
                                                    const float* __restrict__ Wlin,
                                                    const float* __restrict__ blin,
                                                    float* __restrict__ out) {
    int t = threadIdx.x;
    if (t >= NUM_GRAPHS * DOUT) return;
    int g = t / DOUT, o = t % DOUT;
    float inv = 1.0f / fmaxf(cntf[g], 1.0f);
    float acc = 0.f;
    for (int k = 0; k < 2 * DH; ++k)
        acc = fmaf(pool[g * 128 + k], Wlin[k * DOUT + o], acc);
    out[t] = acc * inv + blin[o];
}

extern "C" void kernel_launch(void* const* d_in, const int* in_sizes, int n_in,
                              void* d_out, int out_size, void* d_ws, size_t ws_size,
                              hipStream_t stream) {
    const float* x    = (const float*)d_in[0];
    const int*   ei   = (const int*)d_in[1];
    const int*   batch= (const int*)d_in[2];
    const float* W1   = (const float*)d_in[3];
    const float* b1   = (const float*)d_in[4];
    const float* W2   = (const float*)d_in[5];
    const float* b2   = (const float*)d_in[6];
    const float* Wlin = (const float*)d_in[7];
    const float* blin = (const float*)d_in[8];
    float* out = (float*)d_out;

    const int N = in_sizes[2];            // 50000
    const int E = in_sizes[1] / 2;        // 800000
    const int DIN = in_sizes[0] / N;      // 128
    const int NBUCK = (N + 255) >> BSH;   // 196 buckets of 256 nodes
    const int NBLK = (E + EPB - 1) / EPB; // 98 scatter blocks
    const int L = NBUCK * NBLK;           // hist length (~19.2K)
    const int LB = (L + 255) / 256;       // scan blocks for hist

    // workspace carve-up (256B aligned)
    char* base = (char*)d_ws;
    size_t off = 0;
    auto alloc = [&](size_t bytes) {
        char* p = base + off;
        off = (off + bytes + 255) & ~(size_t)255;
        return p;
    };
    int*   hist   = (int*)  alloc((size_t)L * 4);
    int*   offs   = (int*)  alloc((size_t)L * 4);
    int*   bsum   = (int*)  alloc((size_t)LB * 4);
    int*   rowptr = (int*)  alloc((size_t)(N + 1) * 4);
    float* dinv   = (float*)alloc((size_t)N * 4);
    int*   ebuf   = (int*)  alloc((size_t)E * 4);          // packed (src<<8)|(dst&255)
    int*   csr    = (int*)  alloc((size_t)(E + N) * 4);    // src indices, incl. self
    unsigned short* hb = (unsigned short*)alloc((size_t)N * DH * 2);  // bf16 pre-scaled rows
    float* x1     = (float*)alloc((size_t)N * DH * 4);
    float* x2     = (float*)alloc((size_t)N * DH * 4);
    float* pool   = (float*)alloc((size_t)NUM_GRAPHS * 128 * 4);
    float* cntf   = (float*)alloc((size_t)NUM_GRAPHS * 4);
    (void)ws_size; (void)n_in; (void)out_size; (void)DIN;

    // pool and cntf are adjacent: one memset covers both
    hipMemsetAsync(pool, 0, (size_t)NUM_GRAPHS * 128 * 4 + (size_t)NUM_GRAPHS * 4, stream);

    // CSR build: radix partition (block-private write ranges -> line-local writes)
    hist_kernel<<<NBLK, 256, 0, stream>>>(ei, hist, E, NBLK, NBUCK);
    partial_kernel<<<LB, 256, 0, stream>>>(hist, bsum, L);
    escan_kernel<<<LB, 256, 0, stream>>>(hist, bsum, offs, L);
    scatter_kernel<<<NBLK, 256, 0, stream>>>(ei, offs, ebuf, E, NBLK, NBUCK);
    browfill_kernel<<<NBUCK, 256, 0, stream>>>(ebuf, offs, rowptr, dinv, csr, N, E, NBLK, NBUCK);

    // layer 1: gemm pre-scales rows by dinv and packs bf16
    gemm_kernel<128><<<(N + 63) / 64, 256, 0, stream>>>(x, W1, dinv, hb, N);
    agg_kernel<<<(N + 3) / 4, 256, 0, stream>>>(hb, csr, rowptr, dinv, b1, x1, N);
    // layer 2 (hb buffer reused)
    gemm_kernel<64><<<(N + 63) / 64, 256, 0, stream>>>(x1, W2, dinv, hb, N);
    agg_kernel<<<(N + 3) / 4, 256, 0, stream>>>(hb, csr, rowptr, dinv, b2, x2, N);

    // pooling + head
    const int nodesPerBlock = 32;
    pool_kernel<<<(N + nodesPerBlock - 1) / nodesPerBlock, 128, 0, stream>>>(
        x1, x2, batch, pool, cntf, N, nodesPerBlock);
    final_kernel<<<1, 512, 0, stream>>>(pool, cntf, Wlin, blin, out);
}